// Round 10
// baseline (9382.803 us; speedup 1.0000x reference)
//
#include <hip/hip_runtime.h>
#include <math.h>

#define NT   64
#define NB   16
#define OUTS 256
#define WL   128
#define NC   256
#define NR   4
#define HIDN 512
#define G4   2048
#define WCH  391
#define COUT 927
#define EPSF 1e-6f
#define NBLK 256
#define THR  512

__device__ __forceinline__ float sigf(float x){ return 1.0f/(1.0f+expf(-x)); }
__device__ __forceinline__ float oneplusf(float x){ return fmaxf(x,0.0f)+log1pf(expf(-fabsf(x)))+1.0f; }

__device__ __forceinline__ float waveSum(float v){
#pragma unroll
  for(int o=32;o>0;o>>=1) v += __shfl_down(v,o,64);
  return v;
}
__device__ __forceinline__ float waveMax(float v){
#pragma unroll
  for(int o=32;o>0;o>>=1) v = fmaxf(v,__shfl_down(v,o,64));
  return v;
}

// relaxed agent-scope (LLC-coherent) accessors for cross-block tensors
__device__ __forceinline__ void g_storef(float* p, float v){
  __hip_atomic_store(p, v, __ATOMIC_RELAXED, __HIP_MEMORY_SCOPE_AGENT);
}
__device__ __forceinline__ float g_loadf(const float* p){
  return __hip_atomic_load((float*)p, __ATOMIC_RELAXED, __HIP_MEMORY_SCOPE_AGENT);
}
__device__ __forceinline__ float2 g_loadf2(const float* p){
  unsigned long long v = __hip_atomic_load((const unsigned long long*)p, __ATOMIC_RELAXED, __HIP_MEMORY_SCOPE_AGENT);
  union{unsigned long long u; float2 f;} c; c.u=v; return c.f;
}

// ---- flag protocol (monotonic; producer: syncthreads -> drain -> atomic) ----
__device__ __forceinline__ void waitGE(int* p, int tgt){
  __syncthreads();
  if (threadIdx.x == 0){
    while (__hip_atomic_load(p, __ATOMIC_RELAXED, __HIP_MEMORY_SCOPE_AGENT) < tgt)
      __builtin_amdgcn_s_sleep(2);
    asm volatile("" ::: "memory");
  }
  __syncthreads();
}
__device__ __forceinline__ void sigAdd(int* p){
  __syncthreads();                       // all waves' stores drained (barrier semantics)
  if (threadIdx.x == 0){
    asm volatile("s_waitcnt vmcnt(0) lgkmcnt(0)" ::: "memory");
    __hip_atomic_fetch_add(p, 1, __ATOMIC_RELAXED, __HIP_MEMORY_SCOPE_AGENT);
  }
}
__device__ __forceinline__ void sigSet(int* p, int v){
  __syncthreads();
  if (threadIdx.x == 0){
    asm volatile("s_waitcnt vmcnt(0) lgkmcnt(0)" ::: "memory");
    __hip_atomic_store(p, v, __ATOMIC_RELAXED, __HIP_MEMORY_SCOPE_AGENT);
  }
}

__global__ void k_zero(float* p, size_t n){
  size_t i = (size_t)blockIdx.x*blockDim.x + threadIdx.x;
  size_t st = (size_t)gridDim.x*blockDim.x;
  for(; i<n; i+=st) p[i]=0.0f;
}

// xpart[(t*NB+bi)][2048] = x_t @ Wx[0:256,:]
__global__ __launch_bounds__(256) void k_xpart(
    const float* __restrict__ in_data, const float* __restrict__ Wx, float* __restrict__ xpart)
{
  int jb = blockIdx.x & 15, rt = blockIdx.x >> 4;
  int jg = threadIdx.x & 15, rl = threadIdx.x >> 4;
  int row = rt*16 + rl;
  int j0 = jb*128 + jg*8;
  const float* x = in_data + (size_t)row*256;
  float acc[8];
#pragma unroll
  for(int i=0;i<8;i++) acc[i]=0.0f;
  for(int k=0;k<256;k++){
    float a = x[k];
    const float* w = Wx + (size_t)k*G4 + j0;
    float4 w0 = *(const float4*)w, w1 = *(const float4*)(w+4);
    acc[0]+=a*w0.x; acc[1]+=a*w0.y; acc[2]+=a*w0.z; acc[3]+=a*w0.w;
    acc[4]+=a*w1.x; acc[5]+=a*w1.y; acc[6]+=a*w1.z; acc[7]+=a*w1.w;
  }
  float* xp = xpart + (size_t)row*G4 + j0;
#pragma unroll
  for(int i=0;i<8;i++) xp[i]=acc[i];
}

__global__ __launch_bounds__(THR,1) void k_persist(
    const float* __restrict__ Wx, const float* __restrict__ Wh, const float* __restrict__ b_lstm,
    const float* __restrict__ Wc, const float* __restrict__ bc,
    const float* __restrict__ Wo, const float* __restrict__ bo,
    const float* __restrict__ Wr, const float* __restrict__ br,
    const float* __restrict__ xpart,
    float* mem_g, float* linkT_g, float* rdata_g, float* h_g,
    float* gates_g, float* ctrl_g, float* out_g, int* bar)
{
  __shared__ float s_act[1024];
  __shared__ float s_red[2560];
  __shared__ float s_ctrl[928];
  // leader-persistent state (lives across the whole sequence in LDS)
  __shared__ float s_prd[1024];
  __shared__ float s_c[512];
  __shared__ float s_usage[256], s_prec[256], s_wdist[256];
  __shared__ float s_preold[256];
  __shared__ float s_psi[256], s_u2[256], s_alloc[256], s_wd[256];
  __shared__ float s_rk[256], s_su[256], s_shift[256];
  __shared__ float s_er[128], s_mn[256];
  __shared__ float s_fwd[1024], s_bwd[1024], s_rdl[1024];
  __shared__ float s_scal[32], s_sct[16];

  const int tid = threadIdx.x, blk = blockIdx.x;
  const int b = blk >> 4, s = blk & 15;
  const bool lead = (s == b);
  int* cntA  = bar + b*32 + 0;
  int* cntC  = bar + b*32 + 1;
  int* flagH = bar + b*32 + 2;
  int* flagR = bar + b*32 + 3;

  // zero persistent LDS
  for(int i=tid;i<1024;i+=THR) s_prd[i]=0.f;
  for(int i=tid;i<512;i+=THR)  s_c[i]=0.f;
  for(int i=tid;i<256;i+=THR){ s_usage[i]=0.f; s_prec[i]=0.f; s_wdist[i]=0.f; }
  __syncthreads();

  for(int t=0;t<=NT;t++){
    // ---- wait for rdata(t-1)/h(t-1); stage activations ----
    waitGE(flagR, t);
    if(tid<256){
      float2 v = g_loadf2(rdata_g + b*512 + 2*tid);
      s_act[2*tid]=v.x; s_act[2*tid+1]=v.y;
    } else {
      int i=tid-256;
      float2 v = g_loadf2(h_g + b*512 + 2*i);
      s_act[512+2*i]=v.x; s_act[512+2*i+1]=v.y;
    }
    __syncthreads();
    // ---- gates slice: cols [s*128, s*128+128), full K=1024 ----
    if(t<NT){
      int q4=tid&31, ks=tid>>5;
      int col = s*128 + q4*4;
      float4 acc={0,0,0,0};
      for(int kk=0;kk<64;kk++){
        int k=ks*64+kk;
        float av=s_act[k];
        const float* wr = (k<512) ? (Wx + (size_t)(256+k)*G4) : (Wh + (size_t)(k-512)*G4);
        float4 w4 = *(const float4*)(wr + col);
        acc.x+=av*w4.x; acc.y+=av*w4.y; acc.z+=av*w4.z; acc.w+=av*w4.w;
      }
      int c0=q4*4;
      s_red[ks*128+c0  ]=acc.x; s_red[ks*128+c0+1]=acc.y;
      s_red[ks*128+c0+2]=acc.z; s_red[ks*128+c0+3]=acc.w;
    }
    // ---- out(t-1) slice: cols [s*16, s*16+16) ----
    if(t>0){
      int jl=tid&15, ks2=tid>>4;
      int j=s*16+jl;
      float acc=0;
      for(int kk=0;kk<32;kk++){
        int k=ks2*32+kk;
        float av=s_act[k];
        const float* wr=(k<512)?(Wr+(size_t)k*OUTS):(Wo+(size_t)(k-512)*OUTS);
        acc += av*wr[j];
      }
      s_red[2048 + ks2*16 + jl]=acc;
    }
    __syncthreads();
    if(t<NT && tid<128){
      float g=0;
#pragma unroll
      for(int q=0;q<16;q++) g+=s_red[q*128+tid];
      g_storef(gates_g + b*2048 + s*128 + tid, g);
    }
    if(t>0 && tid<16){
      int j=s*16+tid;
      float acc=bo[j]+br[j];
#pragma unroll
      for(int q=0;q<32;q++) acc+=s_red[2048+q*16+tid];
      out_g[((size_t)(t-1)*NB+b)*OUTS + j]=acc;
    }
    if(t==NT) break;
    sigAdd(cntA);

    // ---- leader: LSTM ----
    if(lead){
      waitGE(cntA, 16*(t+1));
      {
        int jj=tid;
        float g[4];
#pragma unroll
        for(int gg=0;gg<4;gg++){
          int col=gg*512+jj;
          g[gg] = g_loadf(gates_g + b*2048 + col)
                + xpart[((size_t)t*NB+b)*G4 + col] + b_lstm[col];
        }
        float c = sigf(g[1])*s_c[jj] + sigf(g[0])*tanhf(g[2]);
        float h = sigf(g[3])*tanhf(c);
        s_c[jj]=c;
        g_storef(h_g + b*512 + jj, h);
      }
      sigSet(flagH, t+1);
    }
    // ---- all: ctrl slice ----
    waitGE(flagH, t+1);
    if(tid<256){
      float2 v = g_loadf2(h_g + b*512 + 2*tid);
      s_act[2*tid]=v.x; s_act[2*tid+1]=v.y;
    }
    __syncthreads();
    {
      int cl=tid&63, ks=tid>>6;
      int j=s*58+cl;
      float acc=0;
      if(cl<58 && j<COUT){
        for(int kk=0;kk<64;kk++){
          int k=ks*64+kk;
          acc += s_act[k]*Wc[(size_t)k*COUT + j];
        }
      }
      s_red[ks*64+cl]=acc;
    }
    __syncthreads();
    if(tid<58){
      int j=s*58+tid;
      if(j<COUT){
        float a=bc[j];
#pragma unroll
        for(int q=0;q<8;q++) a+=s_red[q*64+tid];
        g_storef(ctrl_g + b*928 + j, fminf(fmaxf(a,-20.f),20.f));
      }
    }
    sigAdd(cntC);

    // ================= leader: full memory step (LDS-local) =================
    if(lead){
      waitGE(cntC, 16*(t+1));
      if(tid<464){
        float2 v = g_loadf2(ctrl_g + b*928 + 2*tid);
        s_ctrl[2*tid]=v.x; s_ctrl[2*tid+1]=v.y;
      }
      __syncthreads();
      if(tid<256){
        int n=tid;
        float psi=1.f;
#pragma unroll
        for(int r=0;r<NR;r++) psi *= 1.f - sigf(s_ctrl[384+r])*s_prd[r*256+n];
        s_psi[n]=psi;
        float uo=s_usage[n], pw=s_wdist[n];
        float u=(uo+pw-uo*pw)*psi;
        s_usage[n]=u;
        s_u2[n]=u*(1.f-EPSF)+EPSF;
      } else if(tid<384){
        int w=tid-256; s_er[w]=sigf(s_ctrl[128+w]);
      } else if(tid>=448){
        int l=tid-448;
        float v=s_ctrl[l]*s_ctrl[l]+s_ctrl[l+64]*s_ctrl[l+64];
        v=waveSum(v);
        if(l==0) s_scal[0]=v;
      }
      __syncthreads();
      // stable rank
      {
        int n=tid&255, hf=tid>>8;
        float u2=s_u2[n]; int c=0;
        for(int jj=0;jj<128;jj++){
          int j=hf*128+jj; float uj=s_u2[j];
          c += (uj<u2)||(uj==u2 && j<n);
        }
        s_red[hf*256+n]=(float)c;
      }
      __syncthreads();
      if(tid<256){
        int rk=(int)(s_red[tid]+s_red[256+tid]);
        s_rk[tid]=(float)rk;
        s_su[rk]=s_u2[tid];
      }
      __syncthreads();
      if(tid<16){
        float run=1.f;
#pragma unroll
        for(int i=0;i<16;i++){ int idx=tid*16+i; s_shift[idx]=run; run*=s_su[idx]; }
        s_sct[tid]=run;
      }
      __syncthreads();
      if(tid==0){
        float run=1.f;
        for(int j=0;j<16;j++){ float t2=s_sct[j]; s_sct[j]=run; run*=t2; }
      }
      __syncthreads();
      if(tid<256){
        int rk=(int)s_rk[tid];
        s_alloc[tid]=(1.f-s_u2[tid])*s_shift[rk]*s_sct[rk>>4];
      }
      // write-key dots + old-mem norms (all 256 rows, halves of w)
      {
        int n=tid&255, hf=tid>>8;
        const float4* mr=(const float4*)(mem_g + ((size_t)(b*256+n))*WL) + hf*16;
        float dt=0,m2=0;
#pragma unroll
        for(int w4=0;w4<16;w4++){
          float4 m=mr[w4]; int w=hf*64+4*w4;
          dt+=m.x*s_ctrl[w]+m.y*s_ctrl[w+1]+m.z*s_ctrl[w+2]+m.w*s_ctrl[w+3];
          m2+=m.x*m.x+m.y*m.y+m.z*m.z+m.w*m.w;
        }
        s_red[hf*256+n]=dt; s_red[512+hf*256+n]=m2;
      }
      __syncthreads();
      if(tid<256){
        float dt=s_red[tid]+s_red[256+tid];
        float m2=s_red[512+tid]+s_red[768+tid];
        float wb=oneplusf(s_ctrl[388]);
        s_red[2048+tid]=dt*wb/(sqrtf(s_scal[0])*sqrtf(m2)+EPSF);
      }
      __syncthreads();
      // write softmax (256 dup over 512)
      {
        float lv=s_red[2048+(tid&255)];
        float mv=waveMax(lv);
        if((tid&63)==0) s_scal[8+(tid>>6)]=mv;
        __syncthreads();
        float mx=s_scal[8]; for(int i=9;i<16;i++) mx=fmaxf(mx,s_scal[i]);
        float ex=expf(lv-mx);
        float sv=waveSum(ex);
        __syncthreads();
        if((tid&63)==0) s_scal[8+(tid>>6)]=sv;
        __syncthreads();
        float se=0; for(int i=8;i<16;i++) se+=s_scal[i]; se*=0.5f;
        if(tid<256){
          float cw=ex/se;
          float ag=sigf(s_ctrl[389]), wg=sigf(s_ctrl[390]);
          float wd=wg*(ag*s_alloc[tid]+(1.f-ag)*cw);
          s_wd[tid]=wd; s_wdist[tid]=wd;
        }
      }
      __syncthreads();
      {
        float wv=waveSum(s_wd[tid&255]);
        if((tid&63)==0) s_scal[8+(tid>>6)]=wv;
        __syncthreads();
        float swd=0; for(int i=8;i<16;i++) swd+=s_scal[i]; swd*=0.5f;
        if(tid<256){
          float po=s_prec[tid];
          s_preold[tid]=po;
          s_prec[tid]=(1.f-swd)*po+s_wd[tid];
        }
      }
      __syncthreads();
      // mem update fused with read-key dots + new norms
      {
        int n=tid&255, hf=tid>>8;
        float ps=s_psi[n], wdn=s_wd[n];
        float4* mr=(float4*)(mem_g + ((size_t)(b*256+n))*WL) + hf*16;
        const float* k0=s_ctrl+WCH;
        const float* k1=s_ctrl+WCH+132;
        const float* k2=s_ctrl+WCH+264;
        const float* k3=s_ctrl+WCH+396;
        float d0=0,d1=0,d2=0,d3=0,m2=0;
#pragma unroll
        for(int w4=0;w4<16;w4++){
          float4 m=mr[w4]; int w=hf*64+4*w4;
          m.x=m.x*ps*(1.f-wdn*s_er[w  ])+wdn*s_ctrl[256+w  ];
          m.y=m.y*ps*(1.f-wdn*s_er[w+1])+wdn*s_ctrl[256+w+1];
          m.z=m.z*ps*(1.f-wdn*s_er[w+2])+wdn*s_ctrl[256+w+2];
          m.w=m.w*ps*(1.f-wdn*s_er[w+3])+wdn*s_ctrl[256+w+3];
          mr[w4]=m;
          d0+=m.x*k0[w]+m.y*k0[w+1]+m.z*k0[w+2]+m.w*k0[w+3];
          d1+=m.x*k1[w]+m.y*k1[w+1]+m.z*k1[w+2]+m.w*k1[w+3];
          d2+=m.x*k2[w]+m.y*k2[w+1]+m.z*k2[w+2]+m.w*k2[w+3];
          d3+=m.x*k3[w]+m.y*k3[w+1]+m.z*k3[w+2]+m.w*k3[w+3];
          m2+=m.x*m.x+m.y*m.y+m.z*m.z+m.w*m.w;
        }
        s_red[(0*2+hf)*256+n]=d0; s_red[(1*2+hf)*256+n]=d1;
        s_red[(2*2+hf)*256+n]=d2; s_red[(3*2+hf)*256+n]=d3;
        s_red[2048+hf*256+n]=m2;
      }
      if(tid<256){   // read-key norms
        int r=tid>>6, l=tid&63;
        const float* kk=s_ctrl+WCH+r*132;
        float kv=kk[l]*kk[l]+kk[l+64]*kk[l+64];
        kv=waveSum(kv);
        if(l==0) s_scal[4+r]=sqrtf(kv);
      }
      __syncthreads();
      if(tid<256){
        int n=tid;
        s_mn[n]=sqrtf(s_red[2048+n]+s_red[2304+n]);
      }
      __syncthreads();
      if(tid<256){
        int n=tid;
#pragma unroll
        for(int r=0;r<NR;r++){
          float d=s_red[(r*2)*256+n]+s_red[(r*2+1)*256+n];
          float rb=oneplusf(s_ctrl[WCH+r*132+128]);
          s_rdl[r*256+n]=d*rb/(s_scal[4+r]*s_mn[n]+EPSF);
        }
      }
      __syncthreads();
      // link update (column n, i-halves) + bwd partials
      {
        int n=tid&255, ih=tid>>8;
        float wdn=s_wd[n], pre=s_preold[n];
        float4* lp=(float4*)(linkT_g+((size_t)(b*256+n))*256) + ih*32;
        float b0=0,b1=0,b2=0,b3=0;
#pragma unroll 4
        for(int q4=0;q4<32;q4++){
          float4 l=lp[q4];
          int i0=ih*128+4*q4;
          float w0=s_wd[i0],w1=s_wd[i0+1],w2=s_wd[i0+2],w3=s_wd[i0+3];
          float4 nl;
          nl.x=(i0  ==n)?0.f:((1.f-w0-wdn)*l.x+w0*pre);
          nl.y=(i0+1==n)?0.f:((1.f-w1-wdn)*l.y+w1*pre);
          nl.z=(i0+2==n)?0.f:((1.f-w2-wdn)*l.z+w2*pre);
          nl.w=(i0+3==n)?0.f:((1.f-w3-wdn)*l.w+w3*pre);
          lp[q4]=nl;
          b0+=nl.x*s_prd[i0]+nl.y*s_prd[i0+1]+nl.z*s_prd[i0+2]+nl.w*s_prd[i0+3];
          b1+=nl.x*s_prd[256+i0]+nl.y*s_prd[256+i0+1]+nl.z*s_prd[256+i0+2]+nl.w*s_prd[256+i0+3];
          b2+=nl.x*s_prd[512+i0]+nl.y*s_prd[512+i0+1]+nl.z*s_prd[512+i0+2]+nl.w*s_prd[512+i0+3];
          b3+=nl.x*s_prd[768+i0]+nl.y*s_prd[768+i0+1]+nl.z*s_prd[768+i0+2]+nl.w*s_prd[768+i0+3];
        }
        s_red[(0*2+ih)*256+n]=b0; s_red[(1*2+ih)*256+n]=b1;
        s_red[(2*2+ih)*256+n]=b2; s_red[(3*2+ih)*256+n]=b3;
      }
      __syncthreads();
      if(tid<256){
#pragma unroll
        for(int r=0;r<NR;r++)
          s_bwd[r*256+tid]=s_red[(r*2)*256+tid]+s_red[(r*2+1)*256+tid];
      }
      __syncthreads();
      // fwd: fwd[r][i] = sum_j linkT[j][i]*prd[r][j]  (coalesced over i)
      {
        int i=tid&255, rh=tid>>8;
        const float* lp = linkT_g + ((size_t)(b*256))*256 + i;
        float f0=0,f1=0;
        for(int j=0;j<256;j++){
          float l = lp[(size_t)j*256];
          f0+=l*s_prd[(2*rh)*256+j];
          f1+=l*s_prd[(2*rh+1)*256+j];
        }
        s_fwd[(2*rh)*256+i]=f0; s_fwd[(2*rh+1)*256+i]=f1;
      }
      __syncthreads();
      // sharpen: wave w -> row (0-3 fwd, 4-7 bwd)
      {
        int l=tid&63, w=tid>>6;
        float* rp=(w<4)? (s_fwd+w*256) : (s_bwd+(w-4)*256);
        float a=rp[l]+EPSF, b2=rp[l+64]+EPSF, c2=rp[l+128]+EPSF, d2=rp[l+192]+EPSF;
        float mxr=waveMax(fmaxf(fmaxf(a,b2),fmaxf(c2,d2)));
        mxr=__shfl(mxr,0,64);
        float ff=oneplusf(s_ctrl[919+w]);
        a=powf(a/mxr,ff); b2=powf(b2/mxr,ff); c2=powf(c2/mxr,ff); d2=powf(d2/mxr,ff);
        float sm=waveSum(a+b2+c2+d2);
        sm=__shfl(sm,0,64);
        float inv=1.f/sm;
        rp[l]=a*inv; rp[l+64]=b2*inv; rp[l+128]=c2*inv; rp[l+192]=d2*inv;
      }
      // read softmax on s_rdl rows (waves 0-3; 4-7 duplicate)
      {
        int l=tid&63, w=tid>>6, row=w&3;
        float* rr=s_rdl+row*256;
        float a=rr[l],b2=rr[l+64],c2=rr[l+128],d2=rr[l+192];
        float mx2=waveMax(fmaxf(fmaxf(a,b2),fmaxf(c2,d2)));
        mx2=__shfl(mx2,0,64);
        a=expf(a-mx2); b2=expf(b2-mx2); c2=expf(c2-mx2); d2=expf(d2-mx2);
        float sm=waveSum(a+b2+c2+d2);
        sm=__shfl(sm,0,64);
        float inv=1.f/sm;
        rr[l]=a*inv; rr[l+64]=b2*inv; rr[l+128]=c2*inv; rr[l+192]=d2*inv;
      }
      __syncthreads();
      if(tid<256){
        int n=tid;
#pragma unroll
        for(int r=0;r<NR;r++){
          float cr=s_rdl[r*256+n];
          float fw=s_fwd[r*256+n];
          float bw=s_bwd[r*256+n];
          int mo=WCH+r*132+129;
          float m0=s_ctrl[mo],m1=s_ctrl[mo+1],m2s=s_ctrl[mo+2];
          float mm=fmaxf(m0,fmaxf(m1,m2s));
          float e0=expf(m0-mm),e1=expf(m1-mm),e2=expf(m2s-mm);
          float es=e0+e1+e2;
          s_prd[r*256+n]=(e0*bw+e1*cr+e2*fw)/es;
        }
      }
      __syncthreads();
      // rdata: rdata[r][w] = sum_n prd[r][n]*mem[n][w]
      {
        int w=tid&127, nq=tid>>7;
        float a0=0,a1=0,a2=0,a3=0;
        const float* mp=mem_g + ((size_t)(b*256))*WL;
        for(int nn=0;nn<64;nn++){
          int n=nq*64+nn;
          float mv=mp[(size_t)n*WL+w];
          a0+=s_prd[n]*mv; a1+=s_prd[256+n]*mv; a2+=s_prd[512+n]*mv; a3+=s_prd[768+n]*mv;
        }
        s_red[(0*4+nq)*128+w]=a0; s_red[(1*4+nq)*128+w]=a1;
        s_red[(2*4+nq)*128+w]=a2; s_red[(3*4+nq)*128+w]=a3;
      }
      __syncthreads();
      {
        int r=tid>>7, w=tid&127;
        float rd=s_red[(r*4+0)*128+w]+s_red[(r*4+1)*128+w]+s_red[(r*4+2)*128+w]+s_red[(r*4+3)*128+w];
        g_storef(rdata_g + b*512 + r*128 + w, rd);
      }
      sigSet(flagR, t+1);
    }
  }
}

extern "C" void kernel_launch(void* const* d_in, const int* in_sizes, int n_in,
                              void* d_out, int out_size, void* d_ws, size_t ws_size,
                              hipStream_t stream) {
  const float* in_data = (const float*)d_in[0];
  const float* Wx      = (const float*)d_in[1];
  const float* Wh      = (const float*)d_in[2];
  const float* b_lstm  = (const float*)d_in[3];
  const float* Wc      = (const float*)d_in[4];
  const float* bc      = (const float*)d_in[5];
  const float* Wo      = (const float*)d_in[6];
  const float* bo      = (const float*)d_in[7];
  const float* Wr      = (const float*)d_in[8];
  const float* br      = (const float*)d_in[9];
  float* out = (float*)d_out;
  float* ws  = (float*)d_ws;

  size_t off=0;
  float* mem_    = ws+off; off += (size_t)NB*NC*WL;        // 524288
  float* linkT_  = ws+off; off += (size_t)NB*NC*NC;        // 1048576
  float* rdata_  = ws+off; off += NB*512;                  // 8192
  float* h_      = ws+off; off += NB*512;                  // 8192
  float* gates_  = ws+off; off += NB*G4;                   // 32768
  float* ctrl_   = ws+off; off += NB*928;                  // 14848
  int*   bar_    = (int*)(ws+off); off += 512;             // flags
  size_t zero_floats = off;                                // ~1.64M floats
  float* xpart_  = ws+off; off += (size_t)NT*NB*G4;        // 2097152
  // total ~3.73M floats = 14.9 MB

  k_zero<<<256,256,0,stream>>>(ws, zero_floats);
  k_xpart<<<1024,256,0,stream>>>(in_data, Wx, xpart_);

  k_persist<<<NBLK,THR,0,stream>>>(Wx,Wh,b_lstm,Wc,bc,Wo,bo,Wr,br,
                                   xpart_,mem_,linkT_,rdata_,h_,
                                   gates_,ctrl_,out,bar_);
}

// Round 13
// 6720.994 us; speedup vs baseline: 1.3960x; 1.3960x over previous
//
#include <hip/hip_runtime.h>
#include <math.h>

#define NT   64
#define NB   16
#define OUTS 256
#define WL   128
#define NC   256
#define NR   4
#define HIDN 512
#define G4   2048
#define KTOT 1280   // gates GEMM K: x(256)+rdata(512)+h(512)
#define WCH  391
#define COUT 927
#define EPSF 1e-6f
#define NBLK 256
#define THR  512
#define NSB  16

__device__ __forceinline__ float sigf(float x){ return 1.0f/(1.0f+expf(-x)); }
__device__ __forceinline__ float oneplusf(float x){ return fmaxf(x,0.0f)+log1pf(expf(-fabsf(x)))+1.0f; }

__device__ __forceinline__ float waveSum(float v){
#pragma unroll
  for(int o=32;o>0;o>>=1) v += __shfl_down(v,o,64);
  return v;
}
__device__ __forceinline__ float waveMax(float v){
#pragma unroll
  for(int o=32;o>0;o>>=1) v = fmaxf(v,__shfl_down(v,o,64));
  return v;
}

__device__ __forceinline__ void g_storef(float* p, float v){
  __hip_atomic_store(p, v, __ATOMIC_RELAXED, __HIP_MEMORY_SCOPE_AGENT);
}
__device__ __forceinline__ float2 g_loadf2(const float* p){
  unsigned long long v = __hip_atomic_load((const unsigned long long*)p, __ATOMIC_RELAXED, __HIP_MEMORY_SCOPE_AGENT);
  union{unsigned long long u; float2 f;} c; c.u=v; return c.f;
}

// per-batch barrier (16 blocks), fence-free protocol validated R3/R5/R8/R9
__device__ __forceinline__ void batbar(int* cnt, int* flg, int phase){
  __syncthreads();
  if (threadIdx.x == 0){
    asm volatile("s_waitcnt vmcnt(0) lgkmcnt(0)" ::: "memory");
    int prev = __hip_atomic_fetch_add(cnt, 1, __ATOMIC_RELAXED, __HIP_MEMORY_SCOPE_AGENT);
    if (prev == NSB*phase - 1){
      __hip_atomic_store(flg, phase, __ATOMIC_RELAXED, __HIP_MEMORY_SCOPE_AGENT);
    } else {
      while (__hip_atomic_load(flg, __ATOMIC_RELAXED, __HIP_MEMORY_SCOPE_AGENT) < phase)
        __builtin_amdgcn_s_sleep(1);
    }
    asm volatile("" ::: "memory");
  }
  __syncthreads();
}

__global__ void k_zero(float* p, size_t n){
  size_t i = (size_t)blockIdx.x*blockDim.x + threadIdx.x;
  size_t st = (size_t)gridDim.x*blockDim.x;
  for(; i<n; i+=st) p[i]=0.0f;
}

// pack gates weights: WgP[s][k][c], c in [0,128) packed col order
// c = q4*4+j  <->  global col = (q4>>3)*512 + s*32 + (q4&7)*4 + j
// k<768 -> Wx row k (x+rdata); k>=768 -> Wh row k-768
__global__ __launch_bounds__(256) void k_packg(
    const float* __restrict__ Wx, const float* __restrict__ Wh, float* __restrict__ WgP)
{
  size_t idx = (size_t)blockIdx.x*256 + threadIdx.x;   // 16*1280*128 = 2,621,440
  int c = (int)(idx & 127);
  int rest = (int)(idx >> 7);
  int k = rest % KTOT;
  int s = rest / KTOT;
  int q4 = c>>2, j = c&3;
  int col = (q4>>3)*512 + s*32 + (q4&7)*4 + j;
  WgP[idx] = (k<768) ? Wx[(size_t)k*G4 + col] : Wh[(size_t)(k-768)*G4 + col];
}

__global__ __launch_bounds__(THR,1) void k_persist(
    const float* __restrict__ WgP, const float* __restrict__ b_lstm,
    const float* __restrict__ Wc, const float* __restrict__ bc,
    const float* __restrict__ Wo, const float* __restrict__ bo,
    const float* __restrict__ Wr, const float* __restrict__ br,
    const float* __restrict__ in_data,
    float* mem_g, float* linkT_g, float* racc_g, float* h_g,
    float* ctrl_g, float* dots_g, float* bwd_g, float* facc_g, float* rlog_g,
    float* out_g, int* bar)
{
  __shared__ float s_act[1280];
  __shared__ float s_red[2560];
  __shared__ float s_ctrl[928];
  // persistent per-block replicated state (never touches global)
  __shared__ float s_prd[1024];      // r_dist
  __shared__ float s_usage[256];
  __shared__ float s_prec[256];
  __shared__ float s_wd[256];        // w_dist (prev until overwritten in D)
  __shared__ float s_cown[32];       // owned LSTM cell slice
  // per-step scratch
  __shared__ float s_psi[256], s_su[256], s_shift[256];
  __shared__ float s_er[128], s_mn[16], s_preo[16];
  __shared__ float s_scal[32], s_sct[16];
  __shared__ float s_link[16*256];   // owned linkT rows (new)
  __shared__ float s_mem[16*128];    // owned mem rows (new)
  __shared__ float s_fwd[1024], s_bwd[1024];

  const int tid = threadIdx.x, blk = blockIdx.x;
  const int s = blk & 15, b = blk >> 4;
  int* cnt = bar + b*32;
  int* flg = bar + b*32 + 16;
  int bcnt = 0;

  for(int i=tid;i<1024;i+=THR) s_prd[i]=0.f;
  for(int i=tid;i<256;i+=THR){ s_usage[i]=0.f; s_prec[i]=0.f; s_wd[i]=0.f; }
  if(tid<32) s_cown[tid]=0.f;
  __syncthreads();

  int myrk=0; float allocv=0.f;

  for(int t=0;t<=NT;t++){
    const float* h_old = h_g + (t&1)*(NB*HIDN);
    float*       h_new = h_g + ((t+1)&1)*(NB*HIDN);

    // ============ PHASE A: stage [x; rdata; h], gates GEMM, LSTM, out(t-1), zero facc ============
    for(int i=tid;i<640;i+=THR){
      int f0=2*i;
      float2 v;
      if(f0<256){
        if(t<NT) v = *(const float2*)(in_data + (size_t)t*NB*256 + b*256 + f0);
        else     v = make_float2(0.f,0.f);
      } else if(f0<768){
        v = g_loadf2(racc_g + b*512 + (f0-256));
      } else {
        v = g_loadf2(h_old + b*HIDN + (f0-768));
      }
      s_act[f0]=v.x; s_act[f0+1]=v.y;
    }
    if(tid<64) g_storef(facc_g + b*1024 + s*64 + tid, 0.0f);
    __syncthreads();
    if(t<NT){
      int q4=tid&31, ks=tid>>5;           // 32 col-quads x 16 k-splits(80)
      const float4* wp = (const float4*)WgP + ((size_t)(s*KTOT) + ks*80)*32 + q4;
      float4 acc={0,0,0,0};
      for(int kk=0;kk<80;kk++){
        float av = s_act[ks*80+kk];
        float4 w4 = wp[(size_t)kk*32];
        acc.x+=av*w4.x; acc.y+=av*w4.y; acc.z+=av*w4.z; acc.w+=av*w4.w;
      }
      *(float4*)&s_red[ks*128 + q4*4] = acc;
    }
    if(t>0){
      int jl=tid&15, ks2=tid>>4;          // 16 j x 32 ksplit(32), K over [rdata;h]
      int j=s*16+jl;
      float acc=0;
      for(int kk=0;kk<32;kk++){
        int k=ks2*32+kk;
        float av=s_act[256+k];
        const float* wr=(k<512)?(Wr+(size_t)k*OUTS):(Wo+(size_t)(k-512)*OUTS);
        acc += av*wr[j];
      }
      s_red[2048 + ks2*16 + jl]=acc;
    }
    __syncthreads();
    if(t<NT && tid<32){
      int jj=tid;
      float g[4];
#pragma unroll
      for(int gg=0;gg<4;gg++){
        float v=0;
#pragma unroll
        for(int q=0;q<16;q++) v += s_red[q*128 + gg*32 + jj];
        v += b_lstm[gg*512 + s*32 + jj];
        g[gg]=v;
      }
      float c = sigf(g[1])*s_cown[jj] + sigf(g[0])*tanhf(g[2]);
      float h = sigf(g[3])*tanhf(c);
      s_cown[jj]=c;
      g_storef(h_new + b*HIDN + s*32 + jj, h);
    }
    if(t>0 && tid>=64 && tid<80){
      int jl=tid-64; int j=s*16+jl;
      float acc=bo[j]+br[j];
#pragma unroll
      for(int q=0;q<32;q++) acc+=s_red[2048 + q*16 + jl];
      out_g[((size_t)(t-1)*NB+b)*OUTS + j]=acc;
    }
    if(t==NT) break;
    batbar(cnt,flg,++bcnt);

    // ============ PHASE B: ctrl = clip(h @ Wc + bc); zero racc ============
    if(tid<256){
      float2 v = g_loadf2(h_new + b*HIDN + 2*tid);
      s_act[2*tid]=v.x; s_act[2*tid+1]=v.y;
    }
    if(tid>=256 && tid<288) g_storef(racc_g + b*512 + s*32 + (tid-256), 0.0f);
    __syncthreads();
    {
      int cl=tid&63, ks=tid>>6;
      int j=s*58+cl;
      float acc=0;
      if(cl<58 && j<COUT){
        for(int kk=0;kk<64;kk++){
          int k=ks*64+kk;
          acc += s_act[k]*Wc[(size_t)k*COUT + j];
        }
      }
      s_red[ks*64+cl]=acc;
    }
    __syncthreads();
    if(tid<58){
      int j=s*58+tid;
      if(j<COUT){
        float a=bc[j];
#pragma unroll
        for(int q=0;q<8;q++) a+=s_red[q*64+tid];
        g_storef(ctrl_g + b*928 + j, fminf(fmaxf(a,-20.f),20.f));
      }
    }
    batbar(cnt,flg,++bcnt);

    // ============ PHASE C: psi/usage/alloc (LDS-persistent) + write-key dots ============
    if(tid<464){
      float2 v = g_loadf2(ctrl_g + b*928 + 2*tid);
      s_ctrl[2*tid]=v.x; s_ctrl[2*tid+1]=v.y;
    }
    __syncthreads();
    if(tid<256){
      int n=tid;
      float psi=1.f;
#pragma unroll
      for(int r=0;r<NR;r++) psi *= 1.f - sigf(s_ctrl[384+r])*s_prd[r*256+n];
      s_psi[n]=psi;
      float uo=s_usage[n], pw=s_wd[n];
      s_usage[n]=(uo+pw-uo*pw)*psi;
    } else if(tid<384){
      int w=tid-256; s_er[w]=sigf(s_ctrl[128+w]);
    } else if(tid>=448){
      int l=tid-448;
      float v=s_ctrl[l]*s_ctrl[l]+s_ctrl[l+64]*s_ctrl[l+64];
      v=waveSum(v);
      if(l==0) s_scal[0]=v;
    }
    __syncthreads();
    {
      int n=tid&255, hf=tid>>8;
      float u2=s_usage[n]*(1.f-EPSF)+EPSF; int c=0;
      for(int jj=0;jj<128;jj++){
        int j=hf*128+jj;
        float uj=s_usage[j]*(1.f-EPSF)+EPSF;
        c += (uj<u2)||(uj==u2 && j<n);
      }
      s_red[hf*256+n]=(float)c;
    }
    __syncthreads();
    if(tid<256){
      myrk=(int)(s_red[tid]+s_red[256+tid]);
      s_su[myrk]=s_usage[tid]*(1.f-EPSF)+EPSF;
    }
    __syncthreads();
    if(tid<16){
      float run=1.f;
#pragma unroll
      for(int i=0;i<16;i++){ int idx=tid*16+i; s_shift[idx]=run; run*=s_su[idx]; }
      s_sct[tid]=run;
    }
    __syncthreads();
    if(tid==0){
      float run=1.f;
      for(int j=0;j<16;j++){ float t2=s_sct[j]; s_sct[j]=run; run*=t2; }
    }
    __syncthreads();
    if(tid<256) allocv=(1.f-s_su[myrk])*s_shift[myrk]*s_sct[myrk>>4];
    {
      int nr=tid>>5, wq=tid&31;
      int n=s*16+nr;
      float4 m=((const float4*)(mem_g + ((size_t)(b*256+n))*WL))[wq];
      int w=wq*4;
      float dt=m.x*s_ctrl[w]+m.y*s_ctrl[w+1]+m.z*s_ctrl[w+2]+m.w*s_ctrl[w+3];
      float m2=m.x*m.x+m.y*m.y+m.z*m.z+m.w*m.w;
      s_red[nr*32+wq]=dt; s_red[512+nr*32+wq]=m2;
    }
    __syncthreads();
    if(tid<16){
      float dt=0,m2=0;
#pragma unroll
      for(int q=0;q<32;q++){ dt+=s_red[tid*32+q]; m2+=s_red[512+tid*32+q]; }
      float wb=oneplusf(s_ctrl[388]);
      float lg=dt*wb/(sqrtf(s_scal[0])*sqrtf(m2)+EPSF);
      g_storef(dots_g+b*256+s*16+tid, lg);
    }
    batbar(cnt,flg,++bcnt);

    // ============ PHASE D: write softmax, prec, link+bwd, fwd->facc, mem, read dots ============
    if(tid<128){
      float2 v=g_loadf2(dots_g+b*256+2*tid);
      s_red[2*tid]=v.x; s_red[2*tid+1]=v.y;
    }
    __syncthreads();
    {
      float lv=s_red[tid&255];
      float mv=waveMax(lv);
      if((tid&63)==0) s_scal[8+(tid>>6)]=mv;
      __syncthreads();
      float mx=s_scal[8]; for(int i=9;i<16;i++) mx=fmaxf(mx,s_scal[i]);
      float ex=expf(lv-mx);
      float sv=waveSum(ex);
      __syncthreads();
      if((tid&63)==0) s_scal[8+(tid>>6)]=sv;
      __syncthreads();
      float se=0; for(int i=8;i<16;i++) se+=s_scal[i]; se*=0.5f;
      if(tid<256){
        float cw=ex/se;
        float ag=sigf(s_ctrl[389]), wg=sigf(s_ctrl[390]);
        s_wd[tid]=wg*(ag*allocv+(1.f-ag)*cw);
      }
    }
    __syncthreads();
    {
      float wv=waveSum(s_wd[tid&255]);
      if((tid&63)==0) s_scal[8+(tid>>6)]=wv;
      __syncthreads();
      float swd=0; for(int i=8;i<16;i++) swd+=s_scal[i]; swd*=0.5f;
      if(tid<16) s_preo[tid]=s_prec[s*16+tid];
      __syncthreads();
      if(tid<256) s_prec[tid]=(1.f-swd)*s_prec[tid]+s_wd[tid];
    }
    __syncthreads();
    {
      int nr=tid>>5, ic=tid&31;
      int n=s*16+nr;
      float wdn=s_wd[n], pre=s_preo[nr];
      float4* lp=(float4*)(linkT_g+((size_t)(b*256+n))*256);
#pragma unroll
      for(int h2=0;h2<2;h2++){
        int i4=ic*2+h2;
        float4 l=lp[i4];
        int i0=i4*4;
        float w0=s_wd[i0],w1=s_wd[i0+1],w2=s_wd[i0+2],w3=s_wd[i0+3];
        float4 nl;
        nl.x=(i0  ==n)?0.f:((1.f-w0-wdn)*l.x+w0*pre);
        nl.y=(i0+1==n)?0.f:((1.f-w1-wdn)*l.y+w1*pre);
        nl.z=(i0+2==n)?0.f:((1.f-w2-wdn)*l.z+w2*pre);
        nl.w=(i0+3==n)?0.f:((1.f-w3-wdn)*l.w+w3*pre);
        lp[i4]=nl;
        *(float4*)&s_link[nr*256+i0]=nl;
      }
    }
    __syncthreads();
    {   // bwd (owned n, full i)
      int nr=tid>>5, ic=tid&31;
      float b0=0,b1=0,b2=0,b3=0;
#pragma unroll
      for(int q=0;q<8;q++){
        int i=ic*8+q;
        float l=s_link[nr*256+i];
        b0+=l*s_prd[i]; b1+=l*s_prd[256+i]; b2+=l*s_prd[512+i]; b3+=l*s_prd[768+i];
      }
      s_red[(0*16+nr)*32+ic]=b0; s_red[(1*16+nr)*32+ic]=b1;
      s_red[(2*16+nr)*32+ic]=b2; s_red[(3*16+nr)*32+ic]=b3;
    }
    __syncthreads();
    if(tid<64){
      int r=tid>>4, nr=tid&15;
      float a=0;
#pragma unroll
      for(int q=0;q<32;q++) a+=s_red[(r*16+nr)*32+q];
      g_storef(bwd_g + b*1024 + r*256 + s*16+nr, a);
    }
    {   // fwd contributions (owned j-slice to all i)
      int np=tid&255, dh=tid>>8;
      float f0=0,f1=0;
#pragma unroll
      for(int jr=0;jr<16;jr++){
        float l=s_link[jr*256+np];
        int j=s*16+jr;
        f0+=l*s_prd[(2*dh)*256+j];
        f1+=l*s_prd[(2*dh+1)*256+j];
      }
      atomicAdd(facc_g + b*1024 + (2*dh)*256 + np, f0);
      atomicAdd(facc_g + b*1024 + (2*dh+1)*256 + np, f1);
    }
    {   // mem update owned rows + LDS stage
      int nr=tid>>5, wq=tid&31;
      int n=s*16+nr;
      float ps=s_psi[n], wdn=s_wd[n];
      float4* mr=(float4*)(mem_g+((size_t)(b*256+n))*WL);
      float4 m=mr[wq]; int w=wq*4;
      m.x=m.x*ps*(1.f-wdn*s_er[w  ])+wdn*s_ctrl[256+w  ];
      m.y=m.y*ps*(1.f-wdn*s_er[w+1])+wdn*s_ctrl[256+w+1];
      m.z=m.z*ps*(1.f-wdn*s_er[w+2])+wdn*s_ctrl[256+w+2];
      m.w=m.w*ps*(1.f-wdn*s_er[w+3])+wdn*s_ctrl[256+w+3];
      mr[wq]=m;
      *(float4*)&s_mem[nr*128+w]=m;
    }
    __syncthreads();
    {   // read-key dots + new mem norms from s_mem
      int nr=tid>>5, wq=tid&31;
      float4 m=*(float4*)&s_mem[nr*128+wq*4];
      int w=wq*4;
      const float* k0=s_ctrl+WCH;
      const float* k1=s_ctrl+WCH+132;
      const float* k2=s_ctrl+WCH+264;
      const float* k3=s_ctrl+WCH+396;
      float d0=m.x*k0[w]+m.y*k0[w+1]+m.z*k0[w+2]+m.w*k0[w+3];
      float d1=m.x*k1[w]+m.y*k1[w+1]+m.z*k1[w+2]+m.w*k1[w+3];
      float d2=m.x*k2[w]+m.y*k2[w+1]+m.z*k2[w+2]+m.w*k2[w+3];
      float d3=m.x*k3[w]+m.y*k3[w+1]+m.z*k3[w+2]+m.w*k3[w+3];
      float m2=m.x*m.x+m.y*m.y+m.z*m.z+m.w*m.w;
      s_red[(0*16+nr)*32+wq]=d0; s_red[(1*16+nr)*32+wq]=d1;
      s_red[(2*16+nr)*32+wq]=d2; s_red[(3*16+nr)*32+wq]=d3;
      s_red[2048+nr*32+wq]=m2;
    }
    if(tid<256){
      int r=tid>>6, l=tid&63;
      const float* kk=s_ctrl+WCH+r*132;
      float kv=kk[l]*kk[l]+kk[l+64]*kk[l+64];
      kv=waveSum(kv);
      if(l==0) s_scal[4+r]=sqrtf(kv);
    }
    __syncthreads();
    if(tid<16){
      float m2=0;
#pragma unroll
      for(int q=0;q<32;q++) m2+=s_red[2048+tid*32+q];
      s_mn[tid]=sqrtf(m2);
    }
    __syncthreads();
    if(tid<64){
      int r=tid>>4, nr=tid&15;
      float dt=0;
#pragma unroll
      for(int q=0;q<32;q++) dt+=s_red[(r*16+nr)*32+q];
      float rb=oneplusf(s_ctrl[WCH+r*132+128]);
      float lg=dt*rb/(s_scal[4+r]*s_mn[nr]+EPSF);
      g_storef(rlog_g+b*1024+r*256+s*16+nr,lg);
    }
    batbar(cnt,flg,++bcnt);

    // ============ PHASE E: sharpen, read softmax, r_dist (LDS), rdata -> racc ============
    {
      float2 v=g_loadf2(facc_g + b*1024 + 2*tid);
      s_fwd[2*tid]=v.x; s_fwd[2*tid+1]=v.y;
    }
    {
      float2 v=g_loadf2(bwd_g+b*1024+2*tid);
      s_bwd[2*tid]=v.x; s_bwd[2*tid+1]=v.y;
    }
    {
      float2 v=g_loadf2(rlog_g+b*1024+2*tid);
      s_red[2*tid]=v.x; s_red[2*tid+1]=v.y;
    }
    __syncthreads();
    {   // sharpen: wave w -> row (0-3 fwd, 4-7 bwd)
      int l=tid&63, w=tid>>6;
      float* rp=(w<4)? (s_fwd+w*256) : (s_bwd+(w-4)*256);
      float a=rp[l]+EPSF, b2=rp[l+64]+EPSF, c2=rp[l+128]+EPSF, d2=rp[l+192]+EPSF;
      float mxr=waveMax(fmaxf(fmaxf(a,b2),fmaxf(c2,d2)));
      mxr=__shfl(mxr,0,64);
      float ff=oneplusf(s_ctrl[919+w]);
      a=powf(a/mxr,ff); b2=powf(b2/mxr,ff); c2=powf(c2/mxr,ff); d2=powf(d2/mxr,ff);
      float sm=waveSum(a+b2+c2+d2);
      sm=__shfl(sm,0,64);
      float inv=1.f/sm;
      rp[l]=a*inv; rp[l+64]=b2*inv; rp[l+128]=c2*inv; rp[l+192]=d2*inv;
    }
    {   // read softmax on s_red rows (dup waves identical)
      int l=tid&63, w=tid>>6, row=w&3;
      float* rr=s_red+row*256;
      float a=rr[l],b2=rr[l+64],c2=rr[l+128],d2=rr[l+192];
      float mx2=waveMax(fmaxf(fmaxf(a,b2),fmaxf(c2,d2)));
      mx2=__shfl(mx2,0,64);
      a=expf(a-mx2); b2=expf(b2-mx2); c2=expf(c2-mx2); d2=expf(d2-mx2);
      float sm=waveSum(a+b2+c2+d2);
      sm=__shfl(sm,0,64);
      float inv=1.f/sm;
      rr[l]=a*inv; rr[l+64]=b2*inv; rr[l+128]=c2*inv; rr[l+192]=d2*inv;
    }
    __syncthreads();
    if(tid<256){
      int n=tid;
#pragma unroll
      for(int r=0;r<NR;r++){
        float cr=s_red[r*256+n];
        float fw=s_fwd[r*256+n];
        float bw=s_bwd[r*256+n];
        int mo=WCH+r*132+129;
        float m0=s_ctrl[mo],m1=s_ctrl[mo+1],m2s=s_ctrl[mo+2];
        float mm=fmaxf(m0,fmaxf(m1,m2s));
        float e0=expf(m0-mm),e1=expf(m1-mm),e2=expf(m2s-mm);
        float es=e0+e1+e2;
        s_prd[r*256+n]=(e0*bw+e1*cr+e2*fw)/es;
      }
    }
    __syncthreads();
    {   // rdata partials over owned rows
      int w=tid&127, nq=tid>>7;
      float a0=0,a1=0,a2=0,a3=0;
#pragma unroll
      for(int q=0;q<4;q++){
        int nr=nq*4+q; int n=s*16+nr;
        float mv=s_mem[nr*128+w];
        a0+=s_prd[n]*mv; a1+=s_prd[256+n]*mv; a2+=s_prd[512+n]*mv; a3+=s_prd[768+n]*mv;
      }
      s_red[(0*4+nq)*128+w]=a0; s_red[(1*4+nq)*128+w]=a1;
      s_red[(2*4+nq)*128+w]=a2; s_red[(3*4+nq)*128+w]=a3;
    }
    __syncthreads();
    {
      int r=tid>>7, w=tid&127;
      float rd=s_red[(r*4+0)*128+w]+s_red[(r*4+1)*128+w]+s_red[(r*4+2)*128+w]+s_red[(r*4+3)*128+w];
      atomicAdd(racc_g + b*512 + r*128 + w, rd);
    }
    batbar(cnt,flg,++bcnt);
  }
}

extern "C" void kernel_launch(void* const* d_in, const int* in_sizes, int n_in,
                              void* d_out, int out_size, void* d_ws, size_t ws_size,
                              hipStream_t stream) {
  const float* in_data = (const float*)d_in[0];
  const float* Wx      = (const float*)d_in[1];
  const float* Wh      = (const float*)d_in[2];
  const float* b_lstm  = (const float*)d_in[3];
  const float* Wc      = (const float*)d_in[4];
  const float* bc      = (const float*)d_in[5];
  const float* Wo      = (const float*)d_in[6];
  const float* bo      = (const float*)d_in[7];
  const float* Wr      = (const float*)d_in[8];
  const float* br      = (const float*)d_in[9];
  float* out = (float*)d_out;
  float* ws  = (float*)d_ws;

  size_t off=0;
  float* mem_    = ws+off; off += (size_t)NB*NC*WL;        // 524288
  float* linkT_  = ws+off; off += (size_t)NB*NC*NC;        // 1048576
  float* racc_   = ws+off; off += NB*512;                  // rdata accumulator
  float* h_      = ws+off; off += 2*NB*HIDN;               // ping-pong
  float* ctrl_   = ws+off; off += NB*928;
  float* dots_   = ws+off; off += NB*NC;
  float* bwd_    = ws+off; off += NB*NR*NC;
  float* facc_   = ws+off; off += NB*NR*NC;                // fwd accumulator
  float* rlog_   = ws+off; off += NB*NR*NC;
  int*   bar_    = (int*)(ws+off); off += 512;
  size_t zero_floats = off;                                // ~1.67M floats
  float* WgP_    = ws+off; off += (size_t)NB*KTOT*128;     // 2,621,440 (packed gates W)
  // total = 4,287,488 floats = 17.15 MB (< R2-proven 17.18 MB)

  k_zero<<<256,256,0,stream>>>(ws, zero_floats);
  k_packg<<<10240,256,0,stream>>>(Wx, Wh, WgP_);

  k_persist<<<NBLK,THR,0,stream>>>(WgP_,b_lstm,Wc,bc,Wo,bo,Wr,br,in_data,
                                   mem_,linkT_,racc_,h_,
                                   ctrl_,dots_,bwd_,facc_,rlog_,out,bar_);
}

// Round 14
// 3798.620 us; speedup vs baseline: 2.4701x; 1.7693x over previous
//
#include <hip/hip_runtime.h>
#include <math.h>

#define NT   64
#define NB   16
#define OUTS 256
#define WL   128
#define NC   256
#define NR   4
#define HIDN 512
#define G4   2048
#define KTOT 1280
#define WCH  391
#define COUT 927
#define EPSF 1e-6f
#define NBLK 256
#define THR  512

// LDS float offsets
#define O_WG    0        // 10240: gates W [k][8]
#define O_WCc   10240    // 2048 : ctrl W [k][4]
#define O_WOc   12288    // 1024 : out W [k2]
#define O_PRD   13312    // 1024 : r_dist (persistent)
#define O_USG   14336    // 256
#define O_PRC   14592    // 256
#define O_WDP   14848    // 256  : w_dist (persistent prev/new)
#define O_COWN  15104    // 32   : LSTM c slice
#define O_RED   15136    // 2560
#define O_SCAL  17696    // 32
#define O_SCT   17728    // 16
#define O_UNI   17744    // 20496 union: phase A/B act  |  phase C/D/E scratch
#define SH_FLOATS 38240  // 152.96 KB

__device__ __forceinline__ float sigf(float x){ return 1.0f/(1.0f+expf(-x)); }
__device__ __forceinline__ float oneplusf(float x){ return fmaxf(x,0.0f)+log1pf(expf(-fabsf(x)))+1.0f; }

__device__ __forceinline__ float waveSum(float v){
#pragma unroll
  for(int o=32;o>0;o>>=1) v += __shfl_down(v,o,64);
  return v;
}
__device__ __forceinline__ float waveMax(float v){
#pragma unroll
  for(int o=32;o>0;o>>=1) v = fmaxf(v,__shfl_down(v,o,64));
  return v;
}

__device__ __forceinline__ void g_storef(float* p, float v){
  __hip_atomic_store(p, v, __ATOMIC_RELAXED, __HIP_MEMORY_SCOPE_AGENT);
}
__device__ __forceinline__ float2 g_loadf2(const float* p){
  unsigned long long v = __hip_atomic_load((const unsigned long long*)p, __ATOMIC_RELAXED, __HIP_MEMORY_SCOPE_AGENT);
  union{unsigned long long u; float2 f;} c; c.u=v; return c.f;
}

// global fence-free barrier (validated protocol; 256 co-resident blocks)
__device__ __forceinline__ void gbar(int* cnt, int* flg, int phase){
  __syncthreads();
  if (threadIdx.x == 0){
    asm volatile("s_waitcnt vmcnt(0) lgkmcnt(0)" ::: "memory");
    int prev = __hip_atomic_fetch_add(cnt, 1, __ATOMIC_RELAXED, __HIP_MEMORY_SCOPE_AGENT);
    if (prev == NBLK*phase - 1){
      __hip_atomic_store(flg, phase, __ATOMIC_RELAXED, __HIP_MEMORY_SCOPE_AGENT);
    } else {
      while (__hip_atomic_load(flg, __ATOMIC_RELAXED, __HIP_MEMORY_SCOPE_AGENT) < phase)
        __builtin_amdgcn_s_sleep(1);
    }
    asm volatile("" ::: "memory");
  }
  __syncthreads();
}

__global__ void k_zero(float* p, size_t n){
  size_t i = (size_t)blockIdx.x*blockDim.x + threadIdx.x;
  size_t st = (size_t)gridDim.x*blockDim.x;
  for(; i<n; i+=st) p[i]=0.0f;
}

__global__ __launch_bounds__(THR,1) void k_persist(
    const float* __restrict__ Wx, const float* __restrict__ Wh, const float* __restrict__ b_lstm,
    const float* __restrict__ Wc, const float* __restrict__ bc,
    const float* __restrict__ Wo, const float* __restrict__ bo,
    const float* __restrict__ Wr, const float* __restrict__ br,
    const float* __restrict__ in_data,
    float* mem_g, float* linkT_g, float* racc_rot, float* h_rot, float* ctrl_rot,
    float* dots_g, float* bwd_g, float* facc_g, float* rlog_g,
    float* out_g, int* bar)
{
  extern __shared__ float SH[];
  float* s_wg   = SH + O_WG;
  float* s_wc   = SH + O_WCc;
  float* s_wo   = SH + O_WOc;
  float* s_prd  = SH + O_PRD;
  float* s_usage= SH + O_USG;
  float* s_prec = SH + O_PRC;
  float* s_wdp  = SH + O_WDP;
  float* s_cown = SH + O_COWN;
  float* s_red  = SH + O_RED;
  float* s_scal = SH + O_SCAL;
  float* s_sct  = SH + O_SCT;
  // union views
  float* s_act  = SH + O_UNI;            // [16][1281]
  float* s_ctrl = SH + O_UNI;            // 928
  float* s_psi  = SH + O_UNI + 928;
  float* s_su   = SH + O_UNI + 1184;
  float* s_shift= SH + O_UNI + 1440;
  float* s_er   = SH + O_UNI + 1696;
  float* s_mn   = SH + O_UNI + 1824;
  float* s_preo = SH + O_UNI + 1840;
  float* s_link = SH + O_UNI + 1856;     // 4096
  float* s_mem  = SH + O_UNI + 5952;     // 2048
  float* s_fwd  = SH + O_UNI + 8000;     // 1024
  float* s_bwd  = SH + O_UNI + 9024;     // 1024

  const int tid = threadIdx.x, bk = blockIdx.x;
  const int s = bk & 15, b = bk >> 4;
  int* cnt = bar;
  int* flg = bar + 32;
  int bcnt = 0;

  // ---- one-time LDS weight loads ----
  for(int i=tid;i<10240;i+=THR){
    int k=i>>3, c=i&7; int g=c>>1, j2=c&1;
    int col = g*512 + 2*bk + j2;
    s_wg[i] = (k<768) ? Wx[(size_t)k*G4+col] : Wh[(size_t)(k-768)*G4+col];
  }
  for(int i=tid;i<2048;i+=THR){
    int k=i>>2, cl=i&3; int j=4*bk+cl;
    s_wc[i] = (bk<232 && j<COUT) ? Wc[(size_t)k*COUT+j] : 0.f;
  }
  for(int i=tid;i<1024;i+=THR){
    s_wo[i] = (i<512) ? Wr[(size_t)i*OUTS+bk] : Wo[(size_t)(i-512)*OUTS+bk];
  }
  for(int i=tid;i<1024;i+=THR) s_prd[i]=0.f;
  for(int i=tid;i<256;i+=THR){ s_usage[i]=0.f; s_prec[i]=0.f; s_wdp[i]=0.f; }
  if(tid<32) s_cown[tid]=0.f;
  __syncthreads();

  int myrk=0; float allocv=0.f;

  for(int t=0;t<=NT;t++){
    // ============ PHASE A: stage act (cached), gates GEMM, LSTM, out(t-1), zero facc ============
    if(t<NT){
      for(int i=tid;i<2048;i+=THR){
        int bi=i>>7, k2=(i&127)*2;
        float2 v = *(const float2*)(in_data + (size_t)t*4096 + bi*256 + k2);
        s_act[bi*1281+k2]=v.x; s_act[bi*1281+k2+1]=v.y;
      }
    }
    for(int i=tid;i<4096;i+=THR){
      int bi=i>>8, k2=(i&255)*2;
      float2 v = *(const float2*)(racc_rot + (size_t)t*8192 + bi*512 + k2);
      s_act[bi*1281+256+k2]=v.x; s_act[bi*1281+256+k2+1]=v.y;
    }
    for(int i=tid;i<4096;i+=THR){
      int bi=i>>8, k2=(i&255)*2;
      float2 v = *(const float2*)(h_rot + (size_t)t*8192 + bi*512 + k2);
      s_act[bi*1281+768+k2]=v.x; s_act[bi*1281+768+k2+1]=v.y;
    }
    if(tid<64) g_storef(facc_g + b*1024 + s*64 + tid, 0.0f);
    __syncthreads();
    if(t<NT){
      int oc=tid&127, q=tid>>7; int c=oc>>4, bi=oc&15;
      const float* ap = s_act + bi*1281;
      const float* wp = s_wg + c;
      float acc=0.f;
      int k0=q*320;
#pragma unroll 8
      for(int it=0;it<320;it++){ int k=k0+it; acc += ap[k]*wp[k*8]; }
      s_red[q*128+oc]=acc;
    }
    if(t>0){
      int bi=tid>>5, q=tid&31;
      const float* ap = s_act + bi*1281 + 256;
      float acc=0.f;
#pragma unroll 8
      for(int it=0;it<32;it++){ int k2=q+it*32; acc += ap[k2]*s_wo[k2]; }
      s_red[512 + bi*32 + q] = acc;
    }
    __syncthreads();
    if(t<NT && tid<32){
      int j2=tid>>4, bi=tid&15;
      float g4[4];
#pragma unroll
      for(int g=0;g<4;g++){
        int c=g*2+j2;
        float v = s_red[0*128+c*16+bi]+s_red[1*128+c*16+bi]+s_red[2*128+c*16+bi]+s_red[3*128+c*16+bi];
        v += b_lstm[g*512 + 2*bk + j2];
        g4[g]=v;
      }
      float cc = sigf(g4[1])*s_cown[j2*16+bi] + sigf(g4[0])*tanhf(g4[2]);
      float hh = sigf(g4[3])*tanhf(cc);
      s_cown[j2*16+bi]=cc;
      g_storef(h_rot + (size_t)(t+1)*8192 + bi*512 + 2*bk + j2, hh);
    }
    if(t>0 && tid>=64 && tid<80){
      int bi=tid-64;
      float acc=bo[bk]+br[bk];
#pragma unroll
      for(int q=0;q<32;q++) acc += s_red[512+bi*32+q];
      out_g[((size_t)(t-1)*NB+bi)*OUTS + bk] = acc;
    }
    if(t==NT) break;
    gbar(cnt,flg,++bcnt);

    // ============ PHASE B: ctrl GEMM (owned 4 cols, all batches) ============
    for(int i=tid;i<4096;i+=THR){
      int bi=i>>8, k2=(i&255)*2;
      float2 v = *(const float2*)(h_rot + (size_t)(t+1)*8192 + bi*512 + k2);
      s_act[bi*1281+768+k2]=v.x; s_act[bi*1281+768+k2+1]=v.y;
    }
    __syncthreads();
    if(bk<232){
      int o=tid&63, ks=tid>>6; int cl=o>>4, bi=o&15;
      int j=4*bk+cl;
      float acc=0.f;
      if(j<COUT){
        const float* ap=s_act+bi*1281+768;
        const float* wp=s_wc+cl;
#pragma unroll 8
        for(int kk=0;kk<64;kk++){ int k=ks*64+kk; acc += ap[k]*wp[k*4]; }
      }
      s_red[ks*64+o]=acc;
    }
    __syncthreads();
    if(bk<232 && tid<64){
      int cl=tid>>4, bi=tid&15; int j=4*bk+cl;
      if(j<COUT){
        float a=bc[j];
#pragma unroll
        for(int ks=0;ks<8;ks++) a+=s_red[ks*64+tid];
        g_storef(ctrl_rot + (size_t)t*14848 + bi*928 + j, fminf(fmaxf(a,-20.f),20.f));
      }
    }
    gbar(cnt,flg,++bcnt);

    // ============ PHASE C: psi/usage/alloc + write-key dots ============
    for(int i=tid;i<464;i+=THR){
      float2 v = *(const float2*)(ctrl_rot + (size_t)t*14848 + b*928 + 2*i);
      s_ctrl[2*i]=v.x; s_ctrl[2*i+1]=v.y;
    }
    __syncthreads();
    if(tid<256){
      int n=tid;
      float psi=1.f;
#pragma unroll
      for(int r=0;r<NR;r++) psi *= 1.f - sigf(s_ctrl[384+r])*s_prd[r*256+n];
      s_psi[n]=psi;
      float uo=s_usage[n], pw=s_wdp[n];
      s_usage[n]=(uo+pw-uo*pw)*psi;
    } else if(tid<384){
      int w=tid-256; s_er[w]=sigf(s_ctrl[128+w]);
    } else if(tid>=448){
      int l=tid-448;
      float v=s_ctrl[l]*s_ctrl[l]+s_ctrl[l+64]*s_ctrl[l+64];
      v=waveSum(v);
      if(l==0) s_scal[0]=v;
    }
    __syncthreads();
    {
      int n=tid&255, hf=tid>>8;
      float u2=s_usage[n]*(1.f-EPSF)+EPSF; int c=0;
      for(int jj=0;jj<128;jj++){
        int j=hf*128+jj;
        float uj=s_usage[j]*(1.f-EPSF)+EPSF;
        c += (uj<u2)||(uj==u2 && j<n);
      }
      s_red[hf*256+n]=(float)c;
    }
    __syncthreads();
    if(tid<256){
      myrk=(int)(s_red[tid]+s_red[256+tid]);
      s_su[myrk]=s_usage[tid]*(1.f-EPSF)+EPSF;
    }
    __syncthreads();
    if(tid<16){
      float run=1.f;
#pragma unroll
      for(int i=0;i<16;i++){ int idx=tid*16+i; s_shift[idx]=run; run*=s_su[idx]; }
      s_sct[tid]=run;
    }
    __syncthreads();
    if(tid==0){
      float run=1.f;
      for(int j=0;j<16;j++){ float t2=s_sct[j]; s_sct[j]=run; run*=t2; }
    }
    __syncthreads();
    if(tid<256) allocv=(1.f-s_su[myrk])*s_shift[myrk]*s_sct[myrk>>4];
    {
      int nr=tid>>5, wq=tid&31;
      int n=s*16+nr;
      float4 m=((const float4*)(mem_g + ((size_t)(b*256+n))*WL))[wq];
      int w=wq*4;
      float dt=m.x*s_ctrl[w]+m.y*s_ctrl[w+1]+m.z*s_ctrl[w+2]+m.w*s_ctrl[w+3];
      float m2=m.x*m.x+m.y*m.y+m.z*m.z+m.w*m.w;
      s_red[nr*32+wq]=dt; s_red[512+nr*32+wq]=m2;
    }
    __syncthreads();
    if(tid<16){
      float dt=0,m2=0;
#pragma unroll
      for(int q=0;q<32;q++){ dt+=s_red[tid*32+q]; m2+=s_red[512+tid*32+q]; }
      float wb=oneplusf(s_ctrl[388]);
      float lg=dt*wb/(sqrtf(s_scal[0])*sqrtf(m2)+EPSF);
      g_storef(dots_g+b*256+s*16+tid, lg);
    }
    gbar(cnt,flg,++bcnt);

    // ============ PHASE D: write softmax, prec, link+bwd, fwd->facc, mem, read dots ============
    if(tid<128){
      float2 v=g_loadf2(dots_g+b*256+2*tid);
      s_red[2*tid]=v.x; s_red[2*tid+1]=v.y;
    }
    __syncthreads();
    {
      float lv=s_red[tid&255];
      float mv=waveMax(lv);
      if((tid&63)==0) s_scal[8+(tid>>6)]=mv;
      __syncthreads();
      float mx=s_scal[8]; for(int i=9;i<16;i++) mx=fmaxf(mx,s_scal[i]);
      float ex=expf(lv-mx);
      float sv=waveSum(ex);
      __syncthreads();
      if((tid&63)==0) s_scal[8+(tid>>6)]=sv;
      __syncthreads();
      float se=0; for(int i=8;i<16;i++) se+=s_scal[i]; se*=0.5f;
      if(tid<256){
        float cw=ex/se;
        float ag=sigf(s_ctrl[389]), wg=sigf(s_ctrl[390]);
        s_wdp[tid]=wg*(ag*allocv+(1.f-ag)*cw);
      }
    }
    __syncthreads();
    {
      float wv=waveSum(s_wdp[tid&255]);
      if((tid&63)==0) s_scal[8+(tid>>6)]=wv;
      __syncthreads();
      float swd=0; for(int i=8;i<16;i++) swd+=s_scal[i]; swd*=0.5f;
      if(tid<16) s_preo[tid]=s_prec[s*16+tid];
      __syncthreads();
      if(tid<256) s_prec[tid]=(1.f-swd)*s_prec[tid]+s_wdp[tid];
    }
    __syncthreads();
    {
      int nr=tid>>5, ic=tid&31;
      int n=s*16+nr;
      float wdn=s_wdp[n], pre=s_preo[nr];
      float4* lp=(float4*)(linkT_g+((size_t)(b*256+n))*256);
#pragma unroll
      for(int h2=0;h2<2;h2++){
        int i4=ic*2+h2;
        float4 l=lp[i4];
        int i0=i4*4;
        float w0=s_wdp[i0],w1=s_wdp[i0+1],w2=s_wdp[i0+2],w3=s_wdp[i0+3];
        float4 nl;
        nl.x=(i0  ==n)?0.f:((1.f-w0-wdn)*l.x+w0*pre);
        nl.y=(i0+1==n)?0.f:((1.f-w1-wdn)*l.y+w1*pre);
        nl.z=(i0+2==n)?0.f:((1.f-w2-wdn)*l.z+w2*pre);
        nl.w=(i0+3==n)?0.f:((1.f-w3-wdn)*l.w+w3*pre);
        lp[i4]=nl;
        *(float4*)&s_link[nr*256+i0]=nl;
      }
    }
    __syncthreads();
    {
      int nr=tid>>5, ic=tid&31;
      float b0=0,b1=0,b2=0,b3=0;
#pragma unroll
      for(int q=0;q<8;q++){
        int i=ic*8+q;
        float l=s_link[nr*256+i];
        b0+=l*s_prd[i]; b1+=l*s_prd[256+i]; b2+=l*s_prd[512+i]; b3+=l*s_prd[768+i];
      }
      s_red[(0*16+nr)*32+ic]=b0; s_red[(1*16+nr)*32+ic]=b1;
      s_red[(2*16+nr)*32+ic]=b2; s_red[(3*16+nr)*32+ic]=b3;
    }
    __syncthreads();
    if(tid<64){
      int r=tid>>4, nr=tid&15;
      float a=0;
#pragma unroll
      for(int q=0;q<32;q++) a+=s_red[(r*16+nr)*32+q];
      g_storef(bwd_g + b*1024 + r*256 + s*16+nr, a);
    }
    {
      int np=tid&255, dh=tid>>8;
      float f0=0,f1=0;
#pragma unroll
      for(int jr=0;jr<16;jr++){
        float l=s_link[jr*256+np];
        int j=s*16+jr;
        f0+=l*s_prd[(2*dh)*256+j];
        f1+=l*s_prd[(2*dh+1)*256+j];
      }
      atomicAdd(facc_g + b*1024 + (2*dh)*256 + np, f0);
      atomicAdd(facc_g + b*1024 + (2*dh+1)*256 + np, f1);
    }
    {
      int nr=tid>>5, wq=tid&31;
      int n=s*16+nr;
      float ps=s_psi[n], wdn=s_wdp[n];
      float4* mr=(float4*)(mem_g+((size_t)(b*256+n))*WL);
      float4 m=mr[wq]; int w=wq*4;
      m.x=m.x*ps*(1.f-wdn*s_er[w  ])+wdn*s_ctrl[256+w  ];
      m.y=m.y*ps*(1.f-wdn*s_er[w+1])+wdn*s_ctrl[256+w+1];
      m.z=m.z*ps*(1.f-wdn*s_er[w+2])+wdn*s_ctrl[256+w+2];
      m.w=m.w*ps*(1.f-wdn*s_er[w+3])+wdn*s_ctrl[256+w+3];
      mr[wq]=m;
      *(float4*)&s_mem[nr*128+w]=m;
    }
    __syncthreads();
    {
      int nr=tid>>5, wq=tid&31;
      float4 m=*(float4*)&s_mem[nr*128+wq*4];
      int w=wq*4;
      const float* k0=s_ctrl+WCH;
      const float* k1=s_ctrl+WCH+132;
      const float* k2=s_ctrl+WCH+264;
      const float* k3=s_ctrl+WCH+396;
      float d0=m.x*k0[w]+m.y*k0[w+1]+m.z*k0[w+2]+m.w*k0[w+3];
      float d1=m.x*k1[w]+m.y*k1[w+1]+m.z*k1[w+2]+m.w*k1[w+3];
      float d2=m.x*k2[w]+m.y*k2[w+1]+m.z*k2[w+2]+m.w*k2[w+3];
      float d3=m.x*k3[w]+m.y*k3[w+1]+m.z*k3[w+2]+m.w*k3[w+3];
      float m2=m.x*m.x+m.y*m.y+m.z*m.z+m.w*m.w;
      s_red[(0*16+nr)*32+wq]=d0; s_red[(1*16+nr)*32+wq]=d1;
      s_red[(2*16+nr)*32+wq]=d2; s_red[(3*16+nr)*32+wq]=d3;
      s_red[2048+nr*32+wq]=m2;
    }
    if(tid<256){
      int r=tid>>6, l=tid&63;
      const float* kk=s_ctrl+WCH+r*132;
      float kv=kk[l]*kk[l]+kk[l+64]*kk[l+64];
      kv=waveSum(kv);
      if(l==0) s_scal[4+r]=sqrtf(kv);
    }
    __syncthreads();
    if(tid<16){
      float m2=0;
#pragma unroll
      for(int q=0;q<32;q++) m2+=s_red[2048+tid*32+q];
      s_mn[tid]=sqrtf(m2);
    }
    __syncthreads();
    if(tid<64){
      int r=tid>>4, nr=tid&15;
      float dt=0;
#pragma unroll
      for(int q=0;q<32;q++) dt+=s_red[(r*16+nr)*32+q];
      float rb=oneplusf(s_ctrl[WCH+r*132+128]);
      float lg=dt*rb/(s_scal[4+r]*s_mn[nr]+EPSF);
      g_storef(rlog_g+b*1024+r*256+s*16+nr,lg);
    }
    gbar(cnt,flg,++bcnt);

    // ============ PHASE E: sharpen, read softmax, r_dist (LDS), rdata -> racc slot t+1 ============
    {
      float2 v=g_loadf2(facc_g + b*1024 + 2*tid);
      s_fwd[2*tid]=v.x; s_fwd[2*tid+1]=v.y;
    }
    {
      float2 v=g_loadf2(bwd_g+b*1024+2*tid);
      s_bwd[2*tid]=v.x; s_bwd[2*tid+1]=v.y;
    }
    {
      float2 v=g_loadf2(rlog_g+b*1024+2*tid);
      s_red[2*tid]=v.x; s_red[2*tid+1]=v.y;
    }
    __syncthreads();
    {
      int l=tid&63, w=tid>>6;
      float* rp=(w<4)? (s_fwd+w*256) : (s_bwd+(w-4)*256);
      float a=rp[l]+EPSF, b2=rp[l+64]+EPSF, c2=rp[l+128]+EPSF, d2=rp[l+192]+EPSF;
      float mxr=waveMax(fmaxf(fmaxf(a,b2),fmaxf(c2,d2)));
      mxr=__shfl(mxr,0,64);
      float ff=oneplusf(s_ctrl[919+w]);
      a=powf(a/mxr,ff); b2=powf(b2/mxr,ff); c2=powf(c2/mxr,ff); d2=powf(d2/mxr,ff);
      float sm=waveSum(a+b2+c2+d2);
      sm=__shfl(sm,0,64);
      float inv=1.f/sm;
      rp[l]=a*inv; rp[l+64]=b2*inv; rp[l+128]=c2*inv; rp[l+192]=d2*inv;
    }
    {
      int l=tid&63, w=tid>>6, row=w&3;
      float* rr=s_red+row*256;
      float a=rr[l],b2=rr[l+64],c2=rr[l+128],d2=rr[l+192];
      float mx2=waveMax(fmaxf(fmaxf(a,b2),fmaxf(c2,d2)));
      mx2=__shfl(mx2,0,64);
      a=expf(a-mx2); b2=expf(b2-mx2); c2=expf(c2-mx2); d2=expf(d2-mx2);
      float sm=waveSum(a+b2+c2+d2);
      sm=__shfl(sm,0,64);
      float inv=1.f/sm;
      rr[l]=a*inv; rr[l+64]=b2*inv; rr[l+128]=c2*inv; rr[l+192]=d2*inv;
    }
    __syncthreads();
    if(tid<256){
      int n=tid;
#pragma unroll
      for(int r=0;r<NR;r++){
        float cr=s_red[r*256+n];
        float fw=s_fwd[r*256+n];
        float bw=s_bwd[r*256+n];
        int mo=WCH+r*132+129;
        float m0=s_ctrl[mo],m1=s_ctrl[mo+1],m2s=s_ctrl[mo+2];
        float mm=fmaxf(m0,fmaxf(m1,m2s));
        float e0=expf(m0-mm),e1=expf(m1-mm),e2=expf(m2s-mm);
        float es=e0+e1+e2;
        s_prd[r*256+n]=(e0*bw+e1*cr+e2*fw)/es;
      }
    }
    __syncthreads();
    {
      int w=tid&127, nq=tid>>7;
      float a0=0,a1=0,a2=0,a3=0;
#pragma unroll
      for(int q=0;q<4;q++){
        int nr=nq*4+q; int n=s*16+nr;
        float mv=s_mem[nr*128+w];
        a0+=s_prd[n]*mv; a1+=s_prd[256+n]*mv; a2+=s_prd[512+n]*mv; a3+=s_prd[768+n]*mv;
      }
      s_red[(0*4+nq)*128+w]=a0; s_red[(1*4+nq)*128+w]=a1;
      s_red[(2*4+nq)*128+w]=a2; s_red[(3*4+nq)*128+w]=a3;
    }
    __syncthreads();
    {
      int r=tid>>7, w=tid&127;
      float rd=s_red[(r*4+0)*128+w]+s_red[(r*4+1)*128+w]+s_red[(r*4+2)*128+w]+s_red[(r*4+3)*128+w];
      atomicAdd(racc_rot + (size_t)(t+1)*8192 + b*512 + r*128 + w, rd);
    }
    gbar(cnt,flg,++bcnt);
  }
}

extern "C" void kernel_launch(void* const* d_in, const int* in_sizes, int n_in,
                              void* d_out, int out_size, void* d_ws, size_t ws_size,
                              hipStream_t stream) {
  const float* in_data = (const float*)d_in[0];
  const float* Wx      = (const float*)d_in[1];
  const float* Wh      = (const float*)d_in[2];
  const float* b_lstm  = (const float*)d_in[3];
  const float* Wc      = (const float*)d_in[4];
  const float* bc      = (const float*)d_in[5];
  const float* Wo      = (const float*)d_in[6];
  const float* bo      = (const float*)d_in[7];
  const float* Wr      = (const float*)d_in[8];
  const float* br      = (const float*)d_in[9];
  float* out = (float*)d_out;
  float* ws  = (float*)d_ws;

  size_t off=0;
  float* mem_     = ws+off; off += (size_t)NB*NC*WL;       // 524288
  float* linkT_   = ws+off; off += (size_t)NB*NC*NC;       // 1048576
  float* racc_rot = ws+off; off += (size_t)65*8192;        // 532480
  float* h_rot    = ws+off; off += (size_t)65*8192;        // 532480
  float* ctrl_rot = ws+off; off += (size_t)64*14848;       // 950272
  float* dots_    = ws+off; off += NB*NC;                  // 4096
  float* bwd_     = ws+off; off += NB*NR*NC;               // 16384
  float* facc_    = ws+off; off += NB*NR*NC;               // 16384
  float* rlog_    = ws+off; off += NB*NR*NC;               // 16384
  int*   bar_     = (int*)(ws+off); off += 512;
  size_t zero_floats = off;                                // 3,641,856 floats = 14.57 MB

  static const size_t SH_BYTES = (size_t)SH_FLOATS*sizeof(float);  // 152,960 B
  hipFuncSetAttribute((const void*)k_persist,
                      hipFuncAttributeMaxDynamicSharedMemorySize, (int)SH_BYTES);

  k_zero<<<256,256,0,stream>>>(ws, zero_floats);
  k_persist<<<NBLK,THR,SH_BYTES,stream>>>(Wx,Wh,b_lstm,Wc,bc,Wo,bo,Wr,br,in_data,
                                          mem_,linkT_,racc_rot,h_rot,ctrl_rot,
                                          dots_,bwd_,facc_,rlog_,out,bar_);
}

// Round 15
// 2868.054 us; speedup vs baseline: 3.2715x; 1.3245x over previous
//
#include <hip/hip_runtime.h>
#include <math.h>

#define NT   64
#define NB   16
#define OUTS 256
#define WL   128
#define NC   256
#define NR   4
#define HIDN 512
#define G4   2048
#define KTOT 1280
#define WCH  391
#define COUT 927
#define EPSF 1e-6f
#define NBLK 256
#define THR  512

// LDS float offsets
#define O_WG    0        // 10240: gates W [c][1280]
#define O_WCc   10240    // 2048 : ctrl W [cl][512]
#define O_WOc   12288    // 1024 : out W [k2]
#define O_PRD   13312    // 1024 : r_dist (persistent)
#define O_USG   14336    // 256
#define O_PRC   14592    // 256
#define O_WDP   14848    // 256
#define O_COWN  15104    // 32
#define O_RED   15136    // 2560
#define O_SCAL  17696    // 32
#define O_SCT   17728    // 16
#define O_UNI   17744    // 20544 union: act[16][1284] | C/D/E scratch
#define SH_FLOATS 38288  // 153,152 B

__device__ __forceinline__ float sigf(float x){ return 1.0f/(1.0f+expf(-x)); }
__device__ __forceinline__ float oneplusf(float x){ return fmaxf(x,0.0f)+log1pf(expf(-fabsf(x)))+1.0f; }

__device__ __forceinline__ float waveSum(float v){
#pragma unroll
  for(int o=32;o>0;o>>=1) v += __shfl_down(v,o,64);
  return v;
}
__device__ __forceinline__ float waveMax(float v){
#pragma unroll
  for(int o=32;o>0;o>>=1) v = fmaxf(v,__shfl_down(v,o,64));
  return v;
}

__device__ __forceinline__ void g_storef(float* p, float v){
  __hip_atomic_store(p, v, __ATOMIC_RELAXED, __HIP_MEMORY_SCOPE_AGENT);
}
__device__ __forceinline__ float2 g_loadf2(const float* p){
  unsigned long long v = __hip_atomic_load((const unsigned long long*)p, __ATOMIC_RELAXED, __HIP_MEMORY_SCOPE_AGENT);
  union{unsigned long long u; float2 f;} c; c.u=v; return c.f;
}

// bar layout (ints): [b*32]=batch global-cnt, [512+b*32]=batch local-cnt,
// [1024+b*32]=batch local-flag, [1536]=global cnt, [1568]=global flag
__device__ __forceinline__ void gbarH(int* bar, int b, int gp){
  __syncthreads();
  if (threadIdx.x == 0){
    asm volatile("s_waitcnt vmcnt(0) lgkmcnt(0)" ::: "memory");
    int prev = __hip_atomic_fetch_add(bar + b*32, 1, __ATOMIC_RELAXED, __HIP_MEMORY_SCOPE_AGENT);
    if (prev == 16*gp - 1){
      int p2 = __hip_atomic_fetch_add(bar + 1536, 1, __ATOMIC_RELAXED, __HIP_MEMORY_SCOPE_AGENT);
      if (p2 == 16*gp - 1)
        __hip_atomic_store(bar + 1568, gp, __ATOMIC_RELAXED, __HIP_MEMORY_SCOPE_AGENT);
    }
    while (__hip_atomic_load(bar + 1568, __ATOMIC_RELAXED, __HIP_MEMORY_SCOPE_AGENT) < gp)
      __builtin_amdgcn_s_sleep(1);
    asm volatile("" ::: "memory");
  }
  __syncthreads();
}
__device__ __forceinline__ void lbar(int* bar, int b, int lp){
  __syncthreads();
  if (threadIdx.x == 0){
    asm volatile("s_waitcnt vmcnt(0) lgkmcnt(0)" ::: "memory");
    int prev = __hip_atomic_fetch_add(bar + 512 + b*32, 1, __ATOMIC_RELAXED, __HIP_MEMORY_SCOPE_AGENT);
    if (prev == 16*lp - 1){
      __hip_atomic_store(bar + 1024 + b*32, lp, __ATOMIC_RELAXED, __HIP_MEMORY_SCOPE_AGENT);
    } else {
      while (__hip_atomic_load(bar + 1024 + b*32, __ATOMIC_RELAXED, __HIP_MEMORY_SCOPE_AGENT) < lp)
        __builtin_amdgcn_s_sleep(1);
    }
    asm volatile("" ::: "memory");
  }
  __syncthreads();
}

__global__ void k_zero(float* p, size_t n){
  size_t i = (size_t)blockIdx.x*blockDim.x + threadIdx.x;
  size_t st = (size_t)gridDim.x*blockDim.x;
  for(; i<n; i+=st) p[i]=0.0f;
}

__global__ __launch_bounds__(THR,1) void k_persist(
    const float* __restrict__ Wx, const float* __restrict__ Wh, const float* __restrict__ b_lstm,
    const float* __restrict__ Wc, const float* __restrict__ bc,
    const float* __restrict__ Wo, const float* __restrict__ bo,
    const float* __restrict__ Wr, const float* __restrict__ br,
    const float* __restrict__ in_data,
    float* mem_g, float* linkT_g, float* racc_rot, float* h_rot, float* ctrl_rot,
    float* dots_g, float* bwd_g, float* facc_g, float* rlog_g,
    float* out_g, int* bar)
{
  extern __shared__ float SH[];
  float* s_wg   = SH + O_WG;
  float* s_wc   = SH + O_WCc;
  float* s_wo   = SH + O_WOc;
  float* s_prd  = SH + O_PRD;
  float* s_usage= SH + O_USG;
  float* s_prec = SH + O_PRC;
  float* s_wdp  = SH + O_WDP;
  float* s_cown = SH + O_COWN;
  float* s_red  = SH + O_RED;
  float* s_scal = SH + O_SCAL;
  float* s_sct  = SH + O_SCT;
  float* s_act  = SH + O_UNI;            // [16][1284]
  float* s_ctrl = SH + O_UNI;
  float* s_psi  = SH + O_UNI + 928;
  float* s_su   = SH + O_UNI + 1184;
  float* s_shift= SH + O_UNI + 1440;
  float* s_er   = SH + O_UNI + 1696;
  float* s_mn   = SH + O_UNI + 1824;
  float* s_preo = SH + O_UNI + 1840;
  float* s_link = SH + O_UNI + 1856;     // 4096
  float* s_mem  = SH + O_UNI + 5952;     // 2048
  float* s_fwd  = SH + O_UNI + 8000;     // 1024
  float* s_bwd  = SH + O_UNI + 9024;     // 1024

  const int tid = threadIdx.x, bk = blockIdx.x;
  const int s = bk & 15, b = bk >> 4;

  // ---- one-time LDS weight loads ----
  for(int i=tid;i<10240;i+=THR){
    int c=i&7, k=i>>3;
    int col=(c>>1)*512 + 2*bk + (c&1);
    s_wg[c*1280+k] = (k<768) ? Wx[(size_t)k*G4+col] : Wh[(size_t)(k-768)*G4+col];
  }
  for(int i=tid;i<2048;i+=THR){
    int cl=i&3, k=i>>2;
    int j=4*bk+cl;
    s_wc[cl*512+k] = (bk<232 && j<COUT) ? Wc[(size_t)k*COUT+j] : 0.f;
  }
  for(int i=tid;i<1024;i+=THR){
    s_wo[i] = (i<512) ? Wr[(size_t)i*OUTS+bk] : Wo[(size_t)(i-512)*OUTS+bk];
  }
  for(int i=tid;i<1024;i+=THR) s_prd[i]=0.f;
  for(int i=tid;i<256;i+=THR){ s_usage[i]=0.f; s_prec[i]=0.f; s_wdp[i]=0.f; }
  if(tid<32) s_cown[tid]=0.f;
  __syncthreads();

  int myrk=0; float allocv=0.f;

  for(int t=0;t<=NT;t++){
    // ============ PHASE A: stage act, gates GEMM, LSTM, out(t-1), zero facc ============
    if(t<NT){
      for(int i=tid;i<2048;i+=THR){
        int bi=i>>7, k2=(i&127)*2;
        float2 v = *(const float2*)(in_data + (size_t)t*4096 + bi*256 + k2);
        s_act[bi*1284+k2]=v.x; s_act[bi*1284+k2+1]=v.y;
      }
    }
    for(int i=tid;i<4096;i+=THR){
      int bi=i>>8, k2=(i&255)*2;
      float2 v = *(const float2*)(racc_rot + (size_t)t*8192 + bi*512 + k2);
      s_act[bi*1284+256+k2]=v.x; s_act[bi*1284+256+k2+1]=v.y;
    }
    for(int i=tid;i<4096;i+=THR){
      int bi=i>>8, k2=(i&255)*2;
      float2 v = *(const float2*)(h_rot + (size_t)t*8192 + bi*512 + k2);
      s_act[bi*1284+768+k2]=v.x; s_act[bi*1284+768+k2+1]=v.y;
    }
    if(tid<64) g_storef(facc_g + b*1024 + s*64 + tid, 0.0f);
    __syncthreads();
    if(t<NT){
      int oc=tid&127, q=tid>>7; int c=oc>>4, bi=oc&15;
      const float* ap = s_act + bi*1284;
      const float* wp = s_wg + c*1280;
      float4 a4={0,0,0,0};
      int k0=q*320;
#pragma unroll 8
      for(int it=0;it<80;it++){
        int k=k0+it*4;
        float4 a=*(const float4*)(ap+k);
        float4 w=*(const float4*)(wp+k);
        a4.x+=a.x*w.x; a4.y+=a.y*w.y; a4.z+=a.z*w.z; a4.w+=a.w*w.w;
      }
      s_red[q*128+oc]=a4.x+a4.y+a4.z+a4.w;
    }
    if(t>0){
      int bi=tid>>5, q=tid&31;
      const float* ap = s_act + bi*1284 + 256;
      float acc=0.f;
#pragma unroll
      for(int it=0;it<8;it++){
        int k2=it*128+q*4;
        float4 a=*(const float4*)(ap+k2);
        float4 w=*(const float4*)(s_wo+k2);
        acc += a.x*w.x+a.y*w.y+a.z*w.z+a.w*w.w;
      }
      s_red[512 + bi*32 + q] = acc;
    }
    __syncthreads();
    if(t<NT && tid<32){
      int j2=tid>>4, bi=tid&15;
      float g4[4];
#pragma unroll
      for(int g=0;g<4;g++){
        int c=g*2+j2;
        float v = s_red[0*128+c*16+bi]+s_red[1*128+c*16+bi]+s_red[2*128+c*16+bi]+s_red[3*128+c*16+bi];
        v += b_lstm[g*512 + 2*bk + j2];
        g4[g]=v;
      }
      float cc = sigf(g4[1])*s_cown[j2*16+bi] + sigf(g4[0])*tanhf(g4[2]);
      float hh = sigf(g4[3])*tanhf(cc);
      s_cown[j2*16+bi]=cc;
      g_storef(h_rot + (size_t)(t+1)*8192 + bi*512 + 2*bk + j2, hh);
    }
    if(t>0 && tid>=64 && tid<80){
      int bi=tid-64;
      float acc=bo[bk]+br[bk];
#pragma unroll
      for(int q=0;q<32;q++) acc += s_red[512+bi*32+q];
      out_g[((size_t)(t-1)*NB+bi)*OUTS + bk] = acc;
    }
    if(t==NT) break;
    gbarH(bar,b,3*t+1);

    // ============ PHASE B: ctrl GEMM (owned 4 cols, all batches) ============
    for(int i=tid;i<4096;i+=THR){
      int bi=i>>8, k2=(i&255)*2;
      float2 v = *(const float2*)(h_rot + (size_t)(t+1)*8192 + bi*512 + k2);
      s_act[bi*1284+768+k2]=v.x; s_act[bi*1284+768+k2+1]=v.y;
    }
    __syncthreads();
    if(bk<232){
      int o=tid&63, ks=tid>>6; int cl=o>>4, bi=o&15;
      int j=4*bk+cl;
      float acc=0.f;
      if(j<COUT){
        const float* ap=s_act+bi*1284+768;
        const float* wp=s_wc+cl*512;
#pragma unroll
        for(int kk=0;kk<16;kk++){
          int k=ks*64+kk*4;
          float4 a=*(const float4*)(ap+k);
          float4 w=*(const float4*)(wp+k);
          acc += a.x*w.x+a.y*w.y+a.z*w.z+a.w*w.w;
        }
      }
      s_red[ks*64+o]=acc;
    }
    __syncthreads();
    if(bk<232 && tid<64){
      int cl=tid>>4, bi=tid&15; int j=4*bk+cl;
      if(j<COUT){
        float a=bc[j];
#pragma unroll
        for(int ks=0;ks<8;ks++) a+=s_red[ks*64+tid];
        g_storef(ctrl_rot + (size_t)t*14848 + bi*928 + j, fminf(fmaxf(a,-20.f),20.f));
      }
    }
    gbarH(bar,b,3*t+2);

    // ============ PHASE C: psi/usage/alloc + write-key dots ============
    for(int i=tid;i<464;i+=THR){
      float2 v = *(const float2*)(ctrl_rot + (size_t)t*14848 + b*928 + 2*i);
      s_ctrl[2*i]=v.x; s_ctrl[2*i+1]=v.y;
    }
    __syncthreads();
    if(tid<256){
      int n=tid;
      float psi=1.f;
#pragma unroll
      for(int r=0;r<NR;r++) psi *= 1.f - sigf(s_ctrl[384+r])*s_prd[r*256+n];
      s_psi[n]=psi;
      float uo=s_usage[n], pw=s_wdp[n];
      s_usage[n]=(uo+pw-uo*pw)*psi;
    } else if(tid<384){
      int w=tid-256; s_er[w]=sigf(s_ctrl[128+w]);
    } else if(tid>=448){
      int l=tid-448;
      float v=s_ctrl[l]*s_ctrl[l]+s_ctrl[l+64]*s_ctrl[l+64];
      v=waveSum(v);
      if(l==0) s_scal[0]=v;
    }
    __syncthreads();
    {
      int n=tid&255, hf=tid>>8;
      float u2=s_usage[n]*(1.f-EPSF)+EPSF; int c=0;
      for(int jj=0;jj<128;jj++){
        int j=hf*128+jj;
        float uj=s_usage[j]*(1.f-EPSF)+EPSF;
        c += (uj<u2)||(uj==u2 && j<n);
      }
      s_red[hf*256+n]=(float)c;
    }
    __syncthreads();
    if(tid<256){
      myrk=(int)(s_red[tid]+s_red[256+tid]);
      s_su[myrk]=s_usage[tid]*(1.f-EPSF)+EPSF;
    }
    __syncthreads();
    if(tid<16){
      float run=1.f;
#pragma unroll
      for(int i=0;i<16;i++){ int idx=tid*16+i; s_shift[idx]=run; run*=s_su[idx]; }
      s_sct[tid]=run;
    }
    __syncthreads();
    if(tid==0){
      float run=1.f;
      for(int j=0;j<16;j++){ float t2=s_sct[j]; s_sct[j]=run; run*=t2; }
    }
    __syncthreads();
    if(tid<256) allocv=(1.f-s_su[myrk])*s_shift[myrk]*s_sct[myrk>>4];
    {
      int nr=tid>>5, wq=tid&31;
      int n=s*16+nr;
      float4 m=((const float4*)(mem_g + ((size_t)(b*256+n))*WL))[wq];
      int w=wq*4;
      float dt=m.x*s_ctrl[w]+m.y*s_ctrl[w+1]+m.z*s_ctrl[w+2]+m.w*s_ctrl[w+3];
      float m2=m.x*m.x+m.y*m.y+m.z*m.z+m.w*m.w;
      s_red[nr*32+wq]=dt; s_red[512+nr*32+wq]=m2;
    }
    __syncthreads();
    if(tid<16){
      float dt=0,m2=0;
#pragma unroll
      for(int q=0;q<32;q++){ dt+=s_red[tid*32+q]; m2+=s_red[512+tid*32+q]; }
      float wb=oneplusf(s_ctrl[388]);
      float lg=dt*wb/(sqrtf(s_scal[0])*sqrtf(m2)+EPSF);
      g_storef(dots_g+b*256+s*16+tid, lg);
    }
    lbar(bar,b,2*t+1);

    // ============ PHASE D: write softmax, prec, link+bwd, fwd->facc, mem, read dots ============
    if(tid<128){
      float2 v=g_loadf2(dots_g+b*256+2*tid);
      s_red[2*tid]=v.x; s_red[2*tid+1]=v.y;
    }
    __syncthreads();
    {
      float lv=s_red[tid&255];
      float mv=waveMax(lv);
      if((tid&63)==0) s_scal[8+(tid>>6)]=mv;
      __syncthreads();
      float mx=s_scal[8]; for(int i=9;i<16;i++) mx=fmaxf(mx,s_scal[i]);
      float ex=expf(lv-mx);
      float sv=waveSum(ex);
      __syncthreads();
      if((tid&63)==0) s_scal[8+(tid>>6)]=sv;
      __syncthreads();
      float se=0; for(int i=8;i<16;i++) se+=s_scal[i]; se*=0.5f;
      if(tid<256){
        float cw=ex/se;
        float ag=sigf(s_ctrl[389]), wg=sigf(s_ctrl[390]);
        s_wdp[tid]=wg*(ag*allocv+(1.f-ag)*cw);
      }
    }
    __syncthreads();
    {
      float wv=waveSum(s_wdp[tid&255]);
      if((tid&63)==0) s_scal[8+(tid>>6)]=wv;
      __syncthreads();
      float swd=0; for(int i=8;i<16;i++) swd+=s_scal[i]; swd*=0.5f;
      if(tid<16) s_preo[tid]=s_prec[s*16+tid];
      __syncthreads();
      if(tid<256) s_prec[tid]=(1.f-swd)*s_prec[tid]+s_wdp[tid];
    }
    __syncthreads();
    {
      int nr=tid>>5, ic=tid&31;
      int n=s*16+nr;
      float wdn=s_wdp[n], pre=s_preo[nr];
      float4* lp=(float4*)(linkT_g+((size_t)(b*256+n))*256);
#pragma unroll
      for(int h2=0;h2<2;h2++){
        int i4=h2*32+ic;
        float4 l=lp[i4];
        int i0=i4*4;
        float4 wv=*(float4*)&s_wdp[i0];
        float4 nl;
        nl.x=(i0  ==n)?0.f:((1.f-wv.x-wdn)*l.x+wv.x*pre);
        nl.y=(i0+1==n)?0.f:((1.f-wv.y-wdn)*l.y+wv.y*pre);
        nl.z=(i0+2==n)?0.f:((1.f-wv.z-wdn)*l.z+wv.z*pre);
        nl.w=(i0+3==n)?0.f:((1.f-wv.w-wdn)*l.w+wv.w*pre);
        lp[i4]=nl;
        *(float4*)&s_link[nr*256+i0]=nl;
      }
    }
    __syncthreads();
    {   // bwd (owned n, i = q*32+ic : bank-conflict-free)
      int nr=tid>>5, ic=tid&31;
      float b0=0,b1=0,b2=0,b3=0;
#pragma unroll
      for(int q=0;q<8;q++){
        int i=q*32+ic;
        float l=s_link[nr*256+i];
        b0+=l*s_prd[i]; b1+=l*s_prd[256+i]; b2+=l*s_prd[512+i]; b3+=l*s_prd[768+i];
      }
      s_red[(0*16+nr)*32+ic]=b0; s_red[(1*16+nr)*32+ic]=b1;
      s_red[(2*16+nr)*32+ic]=b2; s_red[(3*16+nr)*32+ic]=b3;
    }
    __syncthreads();
    if(tid<64){
      int r=tid>>4, nr=tid&15;
      float a=0;
#pragma unroll
      for(int q=0;q<32;q++) a+=s_red[(r*16+nr)*32+q];
      g_storef(bwd_g + b*1024 + r*256 + s*16+nr, a);
    }
    {
      int np=tid&255, dh=tid>>8;
      float f0=0,f1=0;
#pragma unroll
      for(int jr=0;jr<16;jr++){
        float l=s_link[jr*256+np];
        int j=s*16+jr;
        f0+=l*s_prd[(2*dh)*256+j];
        f1+=l*s_prd[(2*dh+1)*256+j];
      }
      atomicAdd(facc_g + b*1024 + (2*dh)*256 + np, f0);
      atomicAdd(facc_g + b*1024 + (2*dh+1)*256 + np, f1);
    }
    {
      int nr=tid>>5, wq=tid&31;
      int n=s*16+nr;
      float ps=s_psi[n], wdn=s_wdp[n];
      float4* mr=(float4*)(mem_g+((size_t)(b*256+n))*WL);
      float4 m=mr[wq]; int w=wq*4;
      m.x=m.x*ps*(1.f-wdn*s_er[w  ])+wdn*s_ctrl[256+w  ];
      m.y=m.y*ps*(1.f-wdn*s_er[w+1])+wdn*s_ctrl[256+w+1];
      m.z=m.z*ps*(1.f-wdn*s_er[w+2])+wdn*s_ctrl[256+w+2];
      m.w=m.w*ps*(1.f-wdn*s_er[w+3])+wdn*s_ctrl[256+w+3];
      mr[wq]=m;
      *(float4*)&s_mem[nr*128+w]=m;
    }
    __syncthreads();
    {
      int nr=tid>>5, wq=tid&31;
      float4 m=*(float4*)&s_mem[nr*128+wq*4];
      int w=wq*4;
      const float* k0=s_ctrl+WCH;
      const float* k1=s_ctrl+WCH+132;
      const float* k2=s_ctrl+WCH+264;
      const float* k3=s_ctrl+WCH+396;
      float d0=m.x*k0[w]+m.y*k0[w+1]+m.z*k0[w+2]+m.w*k0[w+3];
      float d1=m.x*k1[w]+m.y*k1[w+1]+m.z*k1[w+2]+m.w*k1[w+3];
      float d2=m.x*k2[w]+m.y*k2[w+1]+m.z*k2[w+2]+m.w*k2[w+3];
      float d3=m.x*k3[w]+m.y*k3[w+1]+m.z*k3[w+2]+m.w*k3[w+3];
      float m2=m.x*m.x+m.y*m.y+m.z*m.z+m.w*m.w;
      s_red[(0*16+nr)*32+wq]=d0; s_red[(1*16+nr)*32+wq]=d1;
      s_red[(2*16+nr)*32+wq]=d2; s_red[(3*16+nr)*32+wq]=d3;
      s_red[2048+nr*32+wq]=m2;
    }
    if(tid<256){
      int r=tid>>6, l=tid&63;
      const float* kk=s_ctrl+WCH+r*132;
      float kv=kk[l]*kk[l]+kk[l+64]*kk[l+64];
      kv=waveSum(kv);
      if(l==0) s_scal[4+r]=sqrtf(kv);
    }
    __syncthreads();
    if(tid<16){
      float m2=0;
#pragma unroll
      for(int q=0;q<32;q++) m2+=s_red[2048+tid*32+q];
      s_mn[tid]=sqrtf(m2);
    }
    __syncthreads();
    if(tid<64){
      int r=tid>>4, nr=tid&15;
      float dt=0;
#pragma unroll
      for(int q=0;q<32;q++) dt+=s_red[(r*16+nr)*32+q];
      float rb=oneplusf(s_ctrl[WCH+r*132+128]);
      float lg=dt*rb/(s_scal[4+r]*s_mn[nr]+EPSF);
      g_storef(rlog_g+b*1024+r*256+s*16+nr,lg);
    }
    lbar(bar,b,2*t+2);

    // ============ PHASE E: sharpen, read softmax, r_dist (LDS), rdata -> racc slot t+1 ============
    {
      float2 v=g_loadf2(facc_g + b*1024 + 2*tid);
      s_fwd[2*tid]=v.x; s_fwd[2*tid+1]=v.y;
    }
    {
      float2 v=g_loadf2(bwd_g+b*1024+2*tid);
      s_bwd[2*tid]=v.x; s_bwd[2*tid+1]=v.y;
    }
    {
      float2 v=g_loadf2(rlog_g+b*1024+2*tid);
      s_red[2*tid]=v.x; s_red[2*tid+1]=v.y;
    }
    __syncthreads();
    {
      int l=tid&63, w=tid>>6;
      float* rp=(w<4)? (s_fwd+w*256) : (s_bwd+(w-4)*256);
      float a=rp[l]+EPSF, b2=rp[l+64]+EPSF, c2=rp[l+128]+EPSF, d2=rp[l+192]+EPSF;
      float mxr=waveMax(fmaxf(fmaxf(a,b2),fmaxf(c2,d2)));
      mxr=__shfl(mxr,0,64);
      float ff=oneplusf(s_ctrl[919+w]);
      a=powf(a/mxr,ff); b2=powf(b2/mxr,ff); c2=powf(c2/mxr,ff); d2=powf(d2/mxr,ff);
      float sm=waveSum(a+b2+c2+d2);
      sm=__shfl(sm,0,64);
      float inv=1.f/sm;
      rp[l]=a*inv; rp[l+64]=b2*inv; rp[l+128]=c2*inv; rp[l+192]=d2*inv;
    }
    {
      int l=tid&63, w=tid>>6, row=w&3;
      float* rr=s_red+row*256;
      float a=rr[l],b2=rr[l+64],c2=rr[l+128],d2=rr[l+192];
      float mx2=waveMax(fmaxf(fmaxf(a,b2),fmaxf(c2,d2)));
      mx2=__shfl(mx2,0,64);
      a=expf(a-mx2); b2=expf(b2-mx2); c2=expf(c2-mx2); d2=expf(d2-mx2);
      float sm=waveSum(a+b2+c2+d2);
      sm=__shfl(sm,0,64);
      float inv=1.f/sm;
      rr[l]=a*inv; rr[l+64]=b2*inv; rr[l+128]=c2*inv; rr[l+192]=d2*inv;
    }
    __syncthreads();
    if(tid<256){
      int n=tid;
#pragma unroll
      for(int r=0;r<NR;r++){
        float cr=s_red[r*256+n];
        float fw=s_fwd[r*256+n];
        float bw=s_bwd[r*256+n];
        int mo=WCH+r*132+129;
        float m0=s_ctrl[mo],m1=s_ctrl[mo+1],m2s=s_ctrl[mo+2];
        float mm=fmaxf(m0,fmaxf(m1,m2s));
        float e0=expf(m0-mm),e1=expf(m1-mm),e2=expf(m2s-mm);
        float es=e0+e1+e2;
        s_prd[r*256+n]=(e0*bw+e1*cr+e2*fw)/es;
      }
    }
    __syncthreads();
    {
      int w=tid&127, nq=tid>>7;
      float a0=0,a1=0,a2=0,a3=0;
#pragma unroll
      for(int q=0;q<4;q++){
        int nr=nq*4+q; int n=s*16+nr;
        float mv=s_mem[nr*128+w];
        a0+=s_prd[n]*mv; a1+=s_prd[256+n]*mv; a2+=s_prd[512+n]*mv; a3+=s_prd[768+n]*mv;
      }
      s_red[(0*4+nq)*128+w]=a0; s_red[(1*4+nq)*128+w]=a1;
      s_red[(2*4+nq)*128+w]=a2; s_red[(3*4+nq)*128+w]=a3;
    }
    __syncthreads();
    {
      int r=tid>>7, w=tid&127;
      float rd=s_red[(r*4+0)*128+w]+s_red[(r*4+1)*128+w]+s_red[(r*4+2)*128+w]+s_red[(r*4+3)*128+w];
      atomicAdd(racc_rot + (size_t)(t+1)*8192 + b*512 + r*128 + w, rd);
    }
    gbarH(bar,b,3*t+3);
  }
}

extern "C" void kernel_launch(void* const* d_in, const int* in_sizes, int n_in,
                              void* d_out, int out_size, void* d_ws, size_t ws_size,
                              hipStream_t stream) {
  const float* in_data = (const float*)d_in[0];
  const float* Wx      = (const float*)d_in[1];
  const float* Wh      = (const float*)d_in[2];
  const float* b_lstm  = (const float*)d_in[3];
  const float* Wc      = (const float*)d_in[4];
  const float* bc      = (const float*)d_in[5];
  const float* Wo      = (const float*)d_in[6];
  const float* bo      = (const float*)d_in[7];
  const float* Wr      = (const float*)d_in[8];
  const float* br      = (const float*)d_in[9];
  float* out = (float*)d_out;
  float* ws  = (float*)d_ws;

  size_t off=0;
  float* mem_     = ws+off; off += (size_t)NB*NC*WL;       // 524288
  float* linkT_   = ws+off; off += (size_t)NB*NC*NC;       // 1048576
  float* racc_rot = ws+off; off += (size_t)65*8192;        // 532480
  float* h_rot    = ws+off; off += (size_t)65*8192;        // 532480
  float* ctrl_rot = ws+off; off += (size_t)64*14848;       // 950272
  float* dots_    = ws+off; off += NB*NC;
  float* bwd_     = ws+off; off += NB*NR*NC;
  float* facc_    = ws+off; off += NB*NR*NC;
  float* rlog_    = ws+off; off += NB*NR*NC;
  int*   bar_     = (int*)(ws+off); off += 2048;
  size_t zero_floats = off;                                // ~3.64M floats = 14.6 MB

  static const size_t SH_BYTES = (size_t)SH_FLOATS*sizeof(float);  // 153,152 B
  hipFuncSetAttribute((const void*)k_persist,
                      hipFuncAttributeMaxDynamicSharedMemorySize, (int)SH_BYTES);

  k_zero<<<256,256,0,stream>>>(ws, zero_floats);
  k_persist<<<NBLK,THR,SH_BYTES,stream>>>(Wx,Wh,b_lstm,Wc,bc,Wo,bo,Wr,br,in_data,
                                          mem_,linkT_,racc_rot,h_rot,ctrl_rot,
                                          dots_,bwd_,facc_,rlog_,out,bar_);
}

// Round 16
// 2807.066 us; speedup vs baseline: 3.3426x; 1.0217x over previous
//
#include <hip/hip_runtime.h>
#include <math.h>

#define NT   64
#define NB   16
#define OUTS 256
#define WL   128
#define NC   256
#define NR   4
#define HIDN 512
#define G4   2048
#define KTOT 1280
#define WCH  391
#define COUT 927
#define EPSF 1e-6f
#define NBLK 256
#define THR  512

// LDS float offsets (weight rows padded off power-of-2 strides)
#define O_WG    0        // 10272: gates W [c][1284]
#define O_WCc   10272    // 2064 : ctrl W [cl][516]
#define O_WOc   12336    // 1024 : out W [k2]
#define O_PRD   13360    // 1024
#define O_USG   14384    // 256
#define O_PRC   14640    // 256
#define O_WDP   14896    // 256
#define O_COWN  15152    // 32
#define O_RED   15184    // 2560
#define O_SCAL  17744    // 32
#define O_SCT   17776    // 16
#define O_UNI   17792    // 20544 union: act[16][1284] | C/D/E scratch
#define SH_FLOATS 38336  // 153,344 B

__device__ __forceinline__ float sigf(float x){ return 1.0f/(1.0f+expf(-x)); }
__device__ __forceinline__ float oneplusf(float x){ return fmaxf(x,0.0f)+log1pf(expf(-fabsf(x)))+1.0f; }

__device__ __forceinline__ float waveSum(float v){
#pragma unroll
  for(int o=32;o>0;o>>=1) v += __shfl_down(v,o,64);
  return v;
}
__device__ __forceinline__ float waveMax(float v){
#pragma unroll
  for(int o=32;o>0;o>>=1) v = fmaxf(v,__shfl_down(v,o,64));
  return v;
}

__device__ __forceinline__ void g_storef(float* p, float v){
  __hip_atomic_store(p, v, __ATOMIC_RELAXED, __HIP_MEMORY_SCOPE_AGENT);
}
__device__ __forceinline__ float2 g_loadf2(const float* p){
  unsigned long long v = __hip_atomic_load((const unsigned long long*)p, __ATOMIC_RELAXED, __HIP_MEMORY_SCOPE_AGENT);
  union{unsigned long long u; float2 f;} c; c.u=v; return c.f;
}

// hierarchical barriers (validated R15)
__device__ __forceinline__ void gbarH(int* bar, int b, int gp){
  __syncthreads();
  if (threadIdx.x == 0){
    asm volatile("s_waitcnt vmcnt(0) lgkmcnt(0)" ::: "memory");
    int prev = __hip_atomic_fetch_add(bar + b*32, 1, __ATOMIC_RELAXED, __HIP_MEMORY_SCOPE_AGENT);
    if (prev == 16*gp - 1){
      int p2 = __hip_atomic_fetch_add(bar + 1536, 1, __ATOMIC_RELAXED, __HIP_MEMORY_SCOPE_AGENT);
      if (p2 == 16*gp - 1)
        __hip_atomic_store(bar + 1568, gp, __ATOMIC_RELAXED, __HIP_MEMORY_SCOPE_AGENT);
    }
    while (__hip_atomic_load(bar + 1568, __ATOMIC_RELAXED, __HIP_MEMORY_SCOPE_AGENT) < gp)
      __builtin_amdgcn_s_sleep(1);
    asm volatile("" ::: "memory");
  }
  __syncthreads();
}
__device__ __forceinline__ void lbar(int* bar, int b, int lp){
  __syncthreads();
  if (threadIdx.x == 0){
    asm volatile("s_waitcnt vmcnt(0) lgkmcnt(0)" ::: "memory");
    int prev = __hip_atomic_fetch_add(bar + 512 + b*32, 1, __ATOMIC_RELAXED, __HIP_MEMORY_SCOPE_AGENT);
    if (prev == 16*lp - 1){
      __hip_atomic_store(bar + 1024 + b*32, lp, __ATOMIC_RELAXED, __HIP_MEMORY_SCOPE_AGENT);
    } else {
      while (__hip_atomic_load(bar + 1024 + b*32, __ATOMIC_RELAXED, __HIP_MEMORY_SCOPE_AGENT) < lp)
        __builtin_amdgcn_s_sleep(1);
    }
    asm volatile("" ::: "memory");
  }
  __syncthreads();
}

__global__ void k_zero(float* p, size_t n){
  size_t i = (size_t)blockIdx.x*blockDim.x + threadIdx.x;
  size_t st = (size_t)gridDim.x*blockDim.x;
  for(; i<n; i+=st) p[i]=0.0f;
}

__global__ __launch_bounds__(THR,1) void k_persist(
    const float* __restrict__ Wx, const float* __restrict__ Wh, const float* __restrict__ b_lstm,
    const float* __restrict__ Wc, const float* __restrict__ bc,
    const float* __restrict__ Wo, const float* __restrict__ bo,
    const float* __restrict__ Wr, const float* __restrict__ br,
    const float* __restrict__ in_data,
    float* mem_g, float* linkT_g, float* racc_rot, float* h_rot, float* ctrl_rot,
    float* dots_g, float* bwd_g, float* facc_g, float* rlog_g,
    float* out_g, int* bar)
{
  extern __shared__ float SH[];
  float* s_wg   = SH + O_WG;
  float* s_wc   = SH + O_WCc;
  float* s_wo   = SH + O_WOc;
  float* s_prd  = SH + O_PRD;
  float* s_usage= SH + O_USG;
  float* s_prec = SH + O_PRC;
  float* s_wdp  = SH + O_WDP;
  float* s_cown = SH + O_COWN;
  float* s_red  = SH + O_RED;
  float* s_scal = SH + O_SCAL;
  float* s_sct  = SH + O_SCT;
  float* s_act  = SH + O_UNI;            // [16][1284]
  float* s_ctrl = SH + O_UNI;
  float* s_psi  = SH + O_UNI + 928;
  float* s_su   = SH + O_UNI + 1184;
  float* s_shift= SH + O_UNI + 1440;
  float* s_er   = SH + O_UNI + 1696;
  float* s_mn   = SH + O_UNI + 1824;
  float* s_preo = SH + O_UNI + 1840;
  float* s_link = SH + O_UNI + 1856;     // 4096
  float* s_mem  = SH + O_UNI + 5952;     // 2048
  float* s_fwd  = SH + O_UNI + 8000;     // 1024
  float* s_bwd  = SH + O_UNI + 9024;     // 1024
  float* s_rkey = SH + O_UNI + 10048;    // 528: aligned copy of read keys (rows of 132)

  const int tid = threadIdx.x, bk = blockIdx.x;
  const int s = bk & 15, b = bk >> 4;

  // ---- one-time LDS weight loads (padded rows: conflict-free) ----
  for(int i=tid;i<10240;i+=THR){
    int c=i&7, k=i>>3;
    int col=(c>>1)*512 + 2*bk + (c&1);
    s_wg[c*1284+k] = (k<768) ? Wx[(size_t)k*G4+col] : Wh[(size_t)(k-768)*G4+col];
  }
  for(int i=tid;i<2048;i+=THR){
    int cl=i&3, k=i>>2;
    int j=4*bk+cl;
    s_wc[cl*516+k] = (bk<232 && j<COUT) ? Wc[(size_t)k*COUT+j] : 0.f;
  }
  for(int i=tid;i<1024;i+=THR){
    s_wo[i] = (i<512) ? Wr[(size_t)i*OUTS+bk] : Wo[(size_t)(i-512)*OUTS+bk];
  }
  for(int i=tid;i<1024;i+=THR) s_prd[i]=0.f;
  for(int i=tid;i<256;i+=THR){ s_usage[i]=0.f; s_prec[i]=0.f; s_wdp[i]=0.f; }
  if(tid<32) s_cown[tid]=0.f;
  __syncthreads();

  int myrk=0; float allocv=0.f;

  for(int t=0;t<=NT;t++){
    // ============ PHASE A: stage act, gates GEMM, LSTM, out(t-1), zero facc ============
    if(t<NT){
      for(int i=tid;i<2048;i+=THR){
        int bi=i>>7, k2=(i&127)*2;
        float2 v = *(const float2*)(in_data + (size_t)t*4096 + bi*256 + k2);
        s_act[bi*1284+k2]=v.x; s_act[bi*1284+k2+1]=v.y;
      }
    }
    for(int i=tid;i<4096;i+=THR){
      int bi=i>>8, k2=(i&255)*2;
      float2 v = *(const float2*)(racc_rot + (size_t)t*8192 + bi*512 + k2);
      s_act[bi*1284+256+k2]=v.x; s_act[bi*1284+256+k2+1]=v.y;
    }
    for(int i=tid;i<4096;i+=THR){
      int bi=i>>8, k2=(i&255)*2;
      float2 v = *(const float2*)(h_rot + (size_t)t*8192 + bi*512 + k2);
      s_act[bi*1284+768+k2]=v.x; s_act[bi*1284+768+k2+1]=v.y;
    }
    if(tid<64) g_storef(facc_g + b*1024 + s*64 + tid, 0.0f);
    __syncthreads();
    if(t<NT){
      int oc=tid&127, q=tid>>7; int c=oc>>4, bi=oc&15;
      const float* ap = s_act + bi*1284;
      const float* wp = s_wg + c*1284;
      float4 a4={0,0,0,0};
      int k0=q*320;
#pragma unroll 8
      for(int it=0;it<80;it++){
        int k=k0+it*4;
        float4 a=*(const float4*)(ap+k);
        float4 w=*(const float4*)(wp+k);
        a4.x+=a.x*w.x; a4.y+=a.y*w.y; a4.z+=a.z*w.z; a4.w+=a.w*w.w;
      }
      s_red[q*128+oc]=a4.x+a4.y+a4.z+a4.w;
    }
    if(t>0){
      int bi=tid>>5, q=tid&31;
      const float* ap = s_act + bi*1284 + 256;
      float acc=0.f;
#pragma unroll 8
      for(int it=0;it<32;it++){
        int k2=q+it*32;                 // stride-1 per lane: conflict-free
        acc += ap[k2]*s_wo[k2];
      }
      s_red[512 + bi*32 + q] = acc;
    }
    __syncthreads();
    if(t<NT && tid<32){
      int j2=tid>>4, bi=tid&15;
      float g4[4];
#pragma unroll
      for(int g=0;g<4;g++){
        int c=g*2+j2;
        float v = s_red[0*128+c*16+bi]+s_red[1*128+c*16+bi]+s_red[2*128+c*16+bi]+s_red[3*128+c*16+bi];
        v += b_lstm[g*512 + 2*bk + j2];
        g4[g]=v;
      }
      float cc = sigf(g4[1])*s_cown[j2*16+bi] + sigf(g4[0])*tanhf(g4[2]);
      float hh = sigf(g4[3])*tanhf(cc);
      s_cown[j2*16+bi]=cc;
      g_storef(h_rot + (size_t)(t+1)*8192 + bi*512 + 2*bk + j2, hh);
    }
    if(t>0 && tid>=64 && tid<80){
      int bi=tid-64;
      float acc=bo[bk]+br[bk];
#pragma unroll
      for(int q=0;q<32;q++) acc += s_red[512+bi*32+q];
      out_g[((size_t)(t-1)*NB+bi)*OUTS + bk] = acc;
    }
    if(t==NT) break;
    gbarH(bar,b,3*t+1);

    // ============ PHASE B: ctrl GEMM ============
    for(int i=tid;i<4096;i+=THR){
      int bi=i>>8, k2=(i&255)*2;
      float2 v = *(const float2*)(h_rot + (size_t)(t+1)*8192 + bi*512 + k2);
      s_act[bi*1284+768+k2]=v.x; s_act[bi*1284+768+k2+1]=v.y;
    }
    __syncthreads();
    if(bk<232){
      int o=tid&63, ks=tid>>6; int cl=o>>4, bi=o&15;
      int j=4*bk+cl;
      float acc=0.f;
      if(j<COUT){
        const float* ap=s_act+bi*1284+768;
        const float* wp=s_wc+cl*516;
#pragma unroll
        for(int kk=0;kk<16;kk++){
          int k=ks*64+kk*4;
          float4 a=*(const float4*)(ap+k);
          float4 w=*(const float4*)(wp+k);
          acc += a.x*w.x+a.y*w.y+a.z*w.z+a.w*w.w;
        }
      }
      s_red[ks*64+o]=acc;
    }
    __syncthreads();
    if(bk<232 && tid<64){
      int cl=tid>>4, bi=tid&15; int j=4*bk+cl;
      if(j<COUT){
        float a=bc[j];
#pragma unroll
        for(int ks=0;ks<8;ks++) a+=s_red[ks*64+tid];
        g_storef(ctrl_rot + (size_t)t*14848 + bi*928 + j, fminf(fmaxf(a,-20.f),20.f));
      }
    }
    gbarH(bar,b,3*t+2);

    // ============ PHASE C: psi/usage/alloc + write-key dots ============
    for(int i=tid;i<464;i+=THR){
      float2 v = *(const float2*)(ctrl_rot + (size_t)t*14848 + b*928 + 2*i);
      s_ctrl[2*i]=v.x; s_ctrl[2*i+1]=v.y;
    }
    __syncthreads();
    for(int i=tid;i<528;i+=THR) s_rkey[i]=s_ctrl[WCH+i];   // aligned key copy
    if(tid<256){
      int n=tid;
      float psi=1.f;
#pragma unroll
      for(int r=0;r<NR;r++) psi *= 1.f - sigf(s_ctrl[384+r])*s_prd[r*256+n];
      s_psi[n]=psi;
      float uo=s_usage[n], pw=s_wdp[n];
      s_usage[n]=(uo+pw-uo*pw)*psi;
    } else if(tid<384){
      int w=tid-256; s_er[w]=sigf(s_ctrl[128+w]);
    } else if(tid>=448){
      int l=tid-448;
      float v=s_ctrl[l]*s_ctrl[l]+s_ctrl[l+64]*s_ctrl[l+64];
      v=waveSum(v);
      if(l==0) s_scal[0]=v;
    }
    __syncthreads();
    {
      int n=tid&255, hf=tid>>8;
      float u2=s_usage[n]*(1.f-EPSF)+EPSF; int c=0;
      for(int jj=0;jj<128;jj++){
        int j=hf*128+jj;
        float uj=s_usage[j]*(1.f-EPSF)+EPSF;
        c += (uj<u2)||(uj==u2 && j<n);
      }
      s_red[hf*256+n]=(float)c;
    }
    __syncthreads();
    if(tid<256){
      myrk=(int)(s_red[tid]+s_red[256+tid]);
      s_su[myrk]=s_usage[tid]*(1.f-EPSF)+EPSF;
    }
    __syncthreads();
    if(tid<16){
      float run=1.f;
#pragma unroll
      for(int i=0;i<16;i++){ int idx=tid*16+i; s_shift[idx]=run; run*=s_su[idx]; }
      s_sct[tid]=run;
    }
    __syncthreads();
    if(tid==0){
      float run=1.f;
      for(int j=0;j<16;j++){ float t2=s_sct[j]; s_sct[j]=run; run*=t2; }
    }
    __syncthreads();
    if(tid<256) allocv=(1.f-s_su[myrk])*s_shift[myrk]*s_sct[myrk>>4];
    {
      int nr=tid>>5, wq=tid&31;
      int n=s*16+nr;
      float4 m=((const float4*)(mem_g + ((size_t)(b*256+n))*WL))[wq];
      int w=wq*4;
      float4 kk=*(const float4*)(s_ctrl+w);
      float dt=m.x*kk.x+m.y*kk.y+m.z*kk.z+m.w*kk.w;
      float m2=m.x*m.x+m.y*m.y+m.z*m.z+m.w*m.w;
      s_red[nr*32+wq]=dt; s_red[512+nr*32+wq]=m2;
    }
    __syncthreads();
    if(tid<16){
      float dt=0,m2=0;
#pragma unroll
      for(int q=0;q<32;q++){ dt+=s_red[tid*32+q]; m2+=s_red[512+tid*32+q]; }
      float wb=oneplusf(s_ctrl[388]);
      float lg=dt*wb/(sqrtf(s_scal[0])*sqrtf(m2)+EPSF);
      g_storef(dots_g+b*256+s*16+tid, lg);
    }
    lbar(bar,b,2*t+1);

    // ============ PHASE D ============
    if(tid<128){
      float2 v=g_loadf2(dots_g+b*256+2*tid);
      s_red[2*tid]=v.x; s_red[2*tid+1]=v.y;
    }
    __syncthreads();
    {
      float lv=s_red[tid&255];
      float mv=waveMax(lv);
      if((tid&63)==0) s_scal[8+(tid>>6)]=mv;
      __syncthreads();
      float mx=s_scal[8]; for(int i=9;i<16;i++) mx=fmaxf(mx,s_scal[i]);
      float ex=expf(lv-mx);
      float sv=waveSum(ex);
      __syncthreads();
      if((tid&63)==0) s_scal[8+(tid>>6)]=sv;
      __syncthreads();
      float se=0; for(int i=8;i<16;i++) se+=s_scal[i]; se*=0.5f;
      if(tid<256){
        float cw=ex/se;
        float ag=sigf(s_ctrl[389]), wg=sigf(s_ctrl[390]);
        s_wdp[tid]=wg*(ag*allocv+(1.f-ag)*cw);
      }
    }
    __syncthreads();
    {
      float wv=waveSum(s_wdp[tid&255]);
      if((tid&63)==0) s_scal[8+(tid>>6)]=wv;
      __syncthreads();
      float swd=0; for(int i=8;i<16;i++) swd+=s_scal[i]; swd*=0.5f;
      if(tid<16) s_preo[tid]=s_prec[s*16+tid];
      __syncthreads();
      if(tid<256) s_prec[tid]=(1.f-swd)*s_prec[tid]+s_wdp[tid];
    }
    __syncthreads();
    {
      int nr=tid>>5, ic=tid&31;
      int n=s*16+nr;
      float wdn=s_wdp[n], pre=s_preo[nr];
      float4* lp=(float4*)(linkT_g+((size_t)(b*256+n))*256);
#pragma unroll
      for(int h2=0;h2<2;h2++){
        int i4=h2*32+ic;
        float4 l=lp[i4];
        int i0=i4*4;
        float4 wv=*(float4*)&s_wdp[i0];
        float4 nl;
        nl.x=(i0  ==n)?0.f:((1.f-wv.x-wdn)*l.x+wv.x*pre);
        nl.y=(i0+1==n)?0.f:((1.f-wv.y-wdn)*l.y+wv.y*pre);
        nl.z=(i0+2==n)?0.f:((1.f-wv.z-wdn)*l.z+wv.z*pre);
        nl.w=(i0+3==n)?0.f:((1.f-wv.w-wdn)*l.w+wv.w*pre);
        lp[i4]=nl;
        *(float4*)&s_link[nr*256+i0]=nl;
      }
    }
    __syncthreads();
    {
      int nr=tid>>5, ic=tid&31;
      float b0=0,b1=0,b2=0,b3=0;
#pragma unroll
      for(int q=0;q<8;q++){
        int i=q*32+ic;
        float l=s_link[nr*256+i];
        b0+=l*s_prd[i]; b1+=l*s_prd[256+i]; b2+=l*s_prd[512+i]; b3+=l*s_prd[768+i];
      }
      s_red[(0*16+nr)*32+ic]=b0; s_red[(1*16+nr)*32+ic]=b1;
      s_red[(2*16+nr)*32+ic]=b2; s_red[(3*16+nr)*32+ic]=b3;
    }
    __syncthreads();
    if(tid<64){
      int r=tid>>4, nr=tid&15;
      float a=0;
#pragma unroll
      for(int q=0;q<32;q++) a+=s_red[(r*16+nr)*32+q];
      g_storef(bwd_g + b*1024 + r*256 + s*16+nr, a);
    }
    {
      int np=tid&255, dh=tid>>8;
      float f0=0,f1=0;
#pragma unroll
      for(int jr=0;jr<16;jr++){
        float l=s_link[jr*256+np];
        int j=s*16+jr;
        f0+=l*s_prd[(2*dh)*256+j];
        f1+=l*s_prd[(2*dh+1)*256+j];
      }
      atomicAdd(facc_g + b*1024 + (2*dh)*256 + np, f0);
      atomicAdd(facc_g + b*1024 + (2*dh+1)*256 + np, f1);
    }
    {
      int nr=tid>>5, wq=tid&31;
      int n=s*16+nr;
      float ps=s_psi[n], wdn=s_wdp[n];
      float4* mr=(float4*)(mem_g+((size_t)(b*256+n))*WL);
      float4 m=mr[wq]; int w=wq*4;
      float4 er=*(const float4*)(s_er+w);
      float4 wv=*(const float4*)(s_ctrl+256+w);
      m.x=m.x*ps*(1.f-wdn*er.x)+wdn*wv.x;
      m.y=m.y*ps*(1.f-wdn*er.y)+wdn*wv.y;
      m.z=m.z*ps*(1.f-wdn*er.z)+wdn*wv.z;
      m.w=m.w*ps*(1.f-wdn*er.w)+wdn*wv.w;
      mr[wq]=m;
      *(float4*)&s_mem[nr*128+w]=m;
    }
    __syncthreads();
    {
      int nr=tid>>5, wq=tid&31;
      float4 m=*(float4*)&s_mem[nr*128+wq*4];
      int w=wq*4;
      float4 k0=*(const float4*)(s_rkey+w);
      float4 k1=*(const float4*)(s_rkey+132+w);
      float4 k2=*(const float4*)(s_rkey+264+w);
      float4 k3=*(const float4*)(s_rkey+396+w);
      float d0=m.x*k0.x+m.y*k0.y+m.z*k0.z+m.w*k0.w;
      float d1=m.x*k1.x+m.y*k1.y+m.z*k1.z+m.w*k1.w;
      float d2=m.x*k2.x+m.y*k2.y+m.z*k2.z+m.w*k2.w;
      float d3=m.x*k3.x+m.y*k3.y+m.z*k3.z+m.w*k3.w;
      float m2=m.x*m.x+m.y*m.y+m.z*m.z+m.w*m.w;
      s_red[(0*16+nr)*32+wq]=d0; s_red[(1*16+nr)*32+wq]=d1;
      s_red[(2*16+nr)*32+wq]=d2; s_red[(3*16+nr)*32+wq]=d3;
      s_red[2048+nr*32+wq]=m2;
    }
    if(tid<256){
      int r=tid>>6, l=tid&63;
      const float* kk=s_rkey+r*132;
      float kv=kk[l]*kk[l]+kk[l+64]*kk[l+64];
      kv=waveSum(kv);
      if(l==0) s_scal[4+r]=sqrtf(kv);
    }
    __syncthreads();
    if(tid<16){
      float m2=0;
#pragma unroll
      for(int q=0;q<32;q++) m2+=s_red[2048+tid*32+q];
      s_mn[tid]=sqrtf(m2);
    }
    __syncthreads();
    if(tid<64){
      int r=tid>>4, nr=tid&15;
      float dt=0;
#pragma unroll
      for(int q=0;q<32;q++) dt+=s_red[(r*16+nr)*32+q];
      float rb=oneplusf(s_rkey[r*132+128]);
      float lg=dt*rb/(s_scal[4+r]*s_mn[nr]+EPSF);
      g_storef(rlog_g+b*1024+r*256+s*16+nr,lg);
    }
    lbar(bar,b,2*t+2);

    // ============ PHASE E ============
    {
      float2 v=g_loadf2(facc_g + b*1024 + 2*tid);
      s_fwd[2*tid]=v.x; s_fwd[2*tid+1]=v.y;
    }
    {
      float2 v=g_loadf2(bwd_g+b*1024+2*tid);
      s_bwd[2*tid]=v.x; s_bwd[2*tid+1]=v.y;
    }
    {
      float2 v=g_loadf2(rlog_g+b*1024+2*tid);
      s_red[2*tid]=v.x; s_red[2*tid+1]=v.y;
    }
    __syncthreads();
    {
      int l=tid&63, w=tid>>6;
      float* rp=(w<4)? (s_fwd+w*256) : (s_bwd+(w-4)*256);
      float a=rp[l]+EPSF, b2=rp[l+64]+EPSF, c2=rp[l+128]+EPSF, d2=rp[l+192]+EPSF;
      float mxr=waveMax(fmaxf(fmaxf(a,b2),fmaxf(c2,d2)));
      mxr=__shfl(mxr,0,64);
      float ff=oneplusf(s_ctrl[919+w]);
      a=powf(a/mxr,ff); b2=powf(b2/mxr,ff); c2=powf(c2/mxr,ff); d2=powf(d2/mxr,ff);
      float sm=waveSum(a+b2+c2+d2);
      sm=__shfl(sm,0,64);
      float inv=1.f/sm;
      rp[l]=a*inv; rp[l+64]=b2*inv; rp[l+128]=c2*inv; rp[l+192]=d2*inv;
    }
    {
      int l=tid&63, w=tid>>6, row=w&3;
      float* rr=s_red+row*256;
      float a=rr[l],b2=rr[l+64],c2=rr[l+128],d2=rr[l+192];
      float mx2=waveMax(fmaxf(fmaxf(a,b2),fmaxf(c2,d2)));
      mx2=__shfl(mx2,0,64);
      a=expf(a-mx2); b2=expf(b2-mx2); c2=expf(c2-mx2); d2=expf(d2-mx2);
      float sm=waveSum(a+b2+c2+d2);
      sm=__shfl(sm,0,64);
      float inv=1.f/sm;
      rr[l]=a*inv; rr[l+64]=b2*inv; rr[l+128]=c2*inv; rr[l+192]=d2*inv;
    }
    __syncthreads();
    if(tid<256){
      int n=tid;
#pragma unroll
      for(int r=0;r<NR;r++){
        float cr=s_red[r*256+n];
        float fw=s_fwd[r*256+n];
        float bw=s_bwd[r*256+n];
        int mo=WCH+r*132+129;
        float m0=s_ctrl[mo],m1=s_ctrl[mo+1],m2s=s_ctrl[mo+2];
        float mm=fmaxf(m0,fmaxf(m1,m2s));
        float e0=expf(m0-mm),e1=expf(m1-mm),e2=expf(m2s-mm);
        float es=e0+e1+e2;
        s_prd[r*256+n]=(e0*bw+e1*cr+e2*fw)/es;
      }
    }
    __syncthreads();
    {
      int w=tid&127, nq=tid>>7;
      float a0=0,a1=0,a2=0,a3=0;
#pragma unroll
      for(int q=0;q<4;q++){
        int nr=nq*4+q; int n=s*16+nr;
        float mv=s_mem[nr*128+w];
        a0+=s_prd[n]*mv; a1+=s_prd[256+n]*mv; a2+=s_prd[512+n]*mv; a3+=s_prd[768+n]*mv;
      }
      s_red[(0*4+nq)*128+w]=a0; s_red[(1*4+nq)*128+w]=a1;
      s_red[(2*4+nq)*128+w]=a2; s_red[(3*4+nq)*128+w]=a3;
    }
    __syncthreads();
    {
      int r=tid>>7, w=tid&127;
      float rd=s_red[(r*4+0)*128+w]+s_red[(r*4+1)*128+w]+s_red[(r*4+2)*128+w]+s_red[(r*4+3)*128+w];
      atomicAdd(racc_rot + (size_t)(t+1)*8192 + b*512 + r*128 + w, rd);
    }
    gbarH(bar,b,3*t+3);
  }
}

extern "C" void kernel_launch(void* const* d_in, const int* in_sizes, int n_in,
                              void* d_out, int out_size, void* d_ws, size_t ws_size,
                              hipStream_t stream) {
  const float* in_data = (const float*)d_in[0];
  const float* Wx      = (const float*)d_in[1];
  const float* Wh      = (const float*)d_in[2];
  const float* b_lstm  = (const float*)d_in[3];
  const float* Wc      = (const float*)d_in[4];
  const float* bc      = (const float*)d_in[5];
  const float* Wo      = (const float*)d_in[6];
  const float* bo      = (const float*)d_in[7];
  const float* Wr      = (const float*)d_in[8];
  const float* br      = (const float*)d_in[9];
  float* out = (float*)d_out;
  float* ws  = (float*)d_ws;

  size_t off=0;
  float* mem_     = ws+off; off += (size_t)NB*NC*WL;       // 524288
  float* linkT_   = ws+off; off += (size_t)NB*NC*NC;       // 1048576
  float* racc_rot = ws+off; off += (size_t)65*8192;        // 532480
  float* h_rot    = ws+off; off += (size_t)65*8192;        // 532480
  float* ctrl_rot = ws+off; off += (size_t)64*14848;       // 950272
  float* dots_    = ws+off; off += NB*NC;
  float* bwd_     = ws+off; off += NB*NR*NC;
  float* facc_    = ws+off; off += NB*NR*NC;
  float* rlog_    = ws+off; off += NB*NR*NC;
  int*   bar_     = (int*)(ws+off); off += 2048;
  size_t zero_floats = off;                                // ~3.64M floats = 14.6 MB

  static const size_t SH_BYTES = (size_t)SH_FLOATS*sizeof(float);  // 153,344 B
  hipFuncSetAttribute((const void*)k_persist,
                      hipFuncAttributeMaxDynamicSharedMemorySize, (int)SH_BYTES);

  k_zero<<<256,256,0,stream>>>(ws, zero_floats);
  k_persist<<<NBLK,THR,SH_BYTES,stream>>>(Wx,Wh,b_lstm,Wc,bc,Wo,bo,Wr,br,in_data,
                                          mem_,linkT_,racc_rot,h_rot,ctrl_rot,
                                          dots_,bwd_,facc_,rlog_,out,bar_);
}